// Round 9
// baseline (246.152 us; speedup 1.0000x reference)
//
#include <hip/hip_runtime.h>

typedef _Float16 f16x8 __attribute__((ext_vector_type(8)));
typedef unsigned short u16x8v __attribute__((ext_vector_type(8)));
typedef unsigned short u16x4v __attribute__((ext_vector_type(4)));
typedef float f32x4 __attribute__((ext_vector_type(4)));

constexpr int SEQ = 2048;
constexpr int DIM = 1024;
constexpr int BATCH = 4;
constexpr size_t NBS = (size_t)BATCH * SEQ * DIM;  // 8388608

static __device__ __forceinline__ unsigned short f2h(float f) {
    return __builtin_bit_cast(unsigned short, (_Float16)f);  // RNE
}
static __device__ __forceinline__ float h2f(unsigned short u) {
    return (float)__builtin_bit_cast(_Float16, u);
}
static __device__ __forceinline__ f16x8 ldsld(const unsigned short* p) {
    return __builtin_bit_cast(f16x8, *(const u16x8v*)p);
}
// Async global->LDS, 16B/lane. LDS dest = wave-uniform base + lane*16B.
static __device__ __forceinline__ void gld_lds16(const unsigned short* g, unsigned short* l) {
    __builtin_amdgcn_global_load_lds(
        (const __attribute__((address_space(1))) void*)g,
        (__attribute__((address_space(3))) void*)l, 16, 0, 0);
}

// ---------------------------------------------------------------------------
// cvt + transpose, ONE launch:
//   [0,8192):            X fp32 -> fp16.
//   [8192,8192+3072):    Wq,Wk,Wv fp32 -> fp16 (k-major, as input).
//   [11264,11264+512):   WqT/WkT fp32 -> fp16 TRANSPOSED [e][k] (64x64 LDS
//                        tiles) so mt_gemm can be a standard NT GEMM.
// ---------------------------------------------------------------------------
__global__ __launch_bounds__(256) void cvt_all(
    const float* __restrict__ X,
    const float* __restrict__ W0, const float* __restrict__ W1,
    const float* __restrict__ W2,
    unsigned short* __restrict__ Xf, unsigned short* __restrict__ Wf,
    unsigned short* __restrict__ WqT, unsigned short* __restrict__ WkT)
{
    __shared__ __attribute__((aligned(16))) unsigned short T[64][72];  // 144B rows: 16B-aligned
    const int b = blockIdx.x;
    const int t = threadIdx.x;
    if (b < 11264) {
        const float* src;
        unsigned short* dst;
        int i;
        if (b < 8192) {
            src = X; dst = Xf;
            i = b * 256 + t;
        } else {
            const int wb = b - 8192;
            const int z = wb >> 10;              // 1024 blocks per weight
            src = (z == 0) ? W0 : (z == 1) ? W1 : W2;
            dst = Wf + (size_t)z * DIM * DIM;
            i = (wb & 1023) * 256 + t;
        }
        float4 f = ((const float4*)src)[i];
        u16x4v h;
        h.x = f2h(f.x); h.y = f2h(f.y); h.z = f2h(f.z); h.w = f2h(f.w);
        ((u16x4v*)dst)[i] = h;
        return;
    }
    // ---- transpose blocks ----
    const int tb = b - 11264;                    // 0..511
    const float* src = (tb < 256) ? W0 : W1;     // Wq then Wk
    unsigned short* dst = (tb < 256) ? WqT : WkT;
    const int tile = tb & 255;
    const int tk = (tile >> 4) * 64;             // k tile base
    const int te = (tile & 15) * 64;             // e tile base
    const int cu = t & 15, kr4 = t >> 4;         // read: 16 rows/pass, 4 cols/thread
#pragma unroll
    for (int p = 0; p < 4; ++p) {
        const int k = p * 16 + kr4;
        float4 v = *(const float4*)(src + (size_t)(tk + k) * DIM + te + cu * 4);
        T[cu * 4 + 0][k] = f2h(v.x);
        T[cu * 4 + 1][k] = f2h(v.y);
        T[cu * 4 + 2][k] = f2h(v.z);
        T[cu * 4 + 3][k] = f2h(v.w);
    }
    __syncthreads();
    const int un = t & 7, er = t >> 3;           // write: 32 rows/pass, 16B/thread
#pragma unroll
    for (int p = 0; p < 2; ++p) {
        const int e = p * 32 + er;
        *(u16x8v*)(dst + (size_t)(te + e) * DIM + tk + un * 8) =
            *(const u16x8v*)&T[e][un * 8];
    }
}

// ---------------------------------------------------------------------------
// Mt[e'][e] = sum_k Wk[k][e'] Wq[k][e] as a standard NT GEMM on the
// TRANSPOSED copies: A = WkT [e'][k], B = WqT [e][k]. Same swizzled BK=64
// structure as yv_gemm. Grid (8,8).
// ---------------------------------------------------------------------------
__global__ __launch_bounds__(256) void mt_gemm(
    const unsigned short* __restrict__ WkTp, const unsigned short* __restrict__ WqTp,
    unsigned short* __restrict__ Mt)
{
    __shared__ __attribute__((aligned(16))) unsigned short Ah[128 * 64];
    __shared__ __attribute__((aligned(16))) unsigned short Bh[128 * 64];
    const int m0 = blockIdx.x * 128, n0 = blockIdx.y * 128;  // e' rows, e cols
    const int tid = threadIdx.x;
    const int w = tid >> 6, lane = tid & 63, q = lane >> 4, c = lane & 15;
    const int wrow = (w >> 1) * 64, wcol = (w & 1) * 64;
    const int g8 = lane >> 3;
    const int cu = (lane & 7) ^ g8;
    const int srow = w * 8 + g8;
    const int scol = cu * 8;
    unsigned short* lA = Ah + w * 512;
    unsigned short* lB = Bh + w * 512;
    const int c7 = c & 7;

    f32x4 acc[4][4];
#pragma unroll
    for (int a = 0; a < 4; ++a)
#pragma unroll
        for (int bq = 0; bq < 4; ++bq) acc[a][bq] = (f32x4){0.f, 0.f, 0.f, 0.f};

    for (int k0 = 0; k0 < DIM; k0 += 64) {
        __syncthreads();
        {
            const size_t ga = (size_t)(m0 + srow) * DIM + k0 + scol;
            const size_t gb = (size_t)(n0 + srow) * DIM + k0 + scol;
#pragma unroll
            for (int j = 0; j < 4; ++j) {
                gld_lds16(WkTp + ga + (size_t)(j * 32) * DIM, lA + j * 2048);
                gld_lds16(WqTp + gb + (size_t)(j * 32) * DIM, lB + j * 2048);
            }
        }
        __syncthreads();
#pragma unroll
        for (int kk = 0; kk < 2; ++kk) {
            f16x8 af[4], bf[4];
#pragma unroll
            for (int mi = 0; mi < 4; ++mi)
                af[mi] = ldsld(Ah + (wrow + mi * 16 + c) * 64 + (((kk << 2) + q) ^ c7) * 8);
#pragma unroll
            for (int ni = 0; ni < 4; ++ni)
                bf[ni] = ldsld(Bh + (wcol + ni * 16 + c) * 64 + (((kk << 2) + q) ^ c7) * 8);
#pragma unroll
            for (int mi = 0; mi < 4; ++mi)
#pragma unroll
                for (int ni = 0; ni < 4; ++ni)
                    acc[mi][ni] = __builtin_amdgcn_mfma_f32_16x16x32_f16(af[mi], bf[ni], acc[mi][ni], 0, 0, 0);
        }
    }
#pragma unroll
    for (int mi = 0; mi < 4; ++mi)
#pragma unroll
        for (int ni = 0; ni < 4; ++ni) {
            const int col = n0 + wcol + ni * 16 + c;
#pragma unroll
            for (int r = 0; r < 4; ++r) {
                const int row = m0 + wrow + mi * 16 + q * 4 + r;
                Mt[(size_t)row * DIM + col] = f2h(acc[mi][ni][r]);
            }
        }
}

// ---------------------------------------------------------------------------
// Fused Y/V projection, fp16 MFMA. z=0: Y = NT(Xf, Mt); z=1: V = NT(Xf, Wvf)
// stored transposed Vt[b][d][s]. 128x128 tile, BK=64 swizzled, m fastest.
// ---------------------------------------------------------------------------
__global__ __launch_bounds__(256) void yv_gemm(
    const unsigned short* __restrict__ Xf, const unsigned short* __restrict__ Mt,
    const unsigned short* __restrict__ Wvf,
    unsigned short* __restrict__ Yf, unsigned short* __restrict__ Vt)
{
    __shared__ __attribute__((aligned(16))) unsigned short Ah[128 * 64];
    __shared__ __attribute__((aligned(16))) unsigned short Bh[128 * 64];
    const int m0 = blockIdx.x * 128, n0 = blockIdx.y * 128, z = blockIdx.z;
    const unsigned short* Wz = z ? Wvf : Mt;
    const int tid = threadIdx.x;
    const int w = tid >> 6, lane = tid & 63, q = lane >> 4, c = lane & 15;
    const int wrow = (w >> 1) * 64, wcol = (w & 1) * 64;
    const int g8 = lane >> 3;
    const int cu = (lane & 7) ^ g8;
    const int srow = w * 8 + g8;
    const int scol = cu * 8;
    unsigned short* lA = Ah + w * 512;
    unsigned short* lB = Bh + w * 512;
    const int c7 = c & 7;

    f32x4 acc[4][4];
#pragma unroll
    for (int a = 0; a < 4; ++a)
#pragma unroll
        for (int b = 0; b < 4; ++b) acc[a][b] = (f32x4){0.f, 0.f, 0.f, 0.f};

    for (int k0 = 0; k0 < DIM; k0 += 64) {
        __syncthreads();
        {
            const size_t ga = (size_t)(m0 + srow) * DIM + k0 + scol;
            const size_t gb = (size_t)(n0 + srow) * DIM + k0 + scol;
#pragma unroll
            for (int j = 0; j < 4; ++j) {
                gld_lds16(Xf + ga + (size_t)(j * 32) * DIM, lA + j * 2048);
                gld_lds16(Wz + gb + (size_t)(j * 32) * DIM, lB + j * 2048);
            }
        }
        __syncthreads();
#pragma unroll
        for (int kk = 0; kk < 2; ++kk) {
            f16x8 ah[4], bh[4];
#pragma unroll
            for (int mi = 0; mi < 4; ++mi)
                ah[mi] = ldsld(Ah + (wrow + mi * 16 + c) * 64 + (((kk << 2) + q) ^ c7) * 8);
#pragma unroll
            for (int ni = 0; ni < 4; ++ni)
                bh[ni] = ldsld(Bh + (wcol + ni * 16 + c) * 64 + (((kk << 2) + q) ^ c7) * 8);
#pragma unroll
            for (int mi = 0; mi < 4; ++mi)
#pragma unroll
                for (int ni = 0; ni < 4; ++ni)
                    acc[mi][ni] = __builtin_amdgcn_mfma_f32_16x16x32_f16(ah[mi], bh[ni], acc[mi][ni], 0, 0, 0);
        }
    }

    if (z == 1) {
        // V: store transposed Vt[b][d][s], fp16.
#pragma unroll
        for (int mi = 0; mi < 4; ++mi) {
            const int mg = m0 + wrow + mi * 16 + q * 4;
            const int bb = mg >> 11, ss = mg & (SEQ - 1);
#pragma unroll
            for (int ni = 0; ni < 4; ++ni) {
                const int col = n0 + wcol + ni * 16 + c;
                u16x4v v;
                v.x = f2h(acc[mi][ni][0]);
                v.y = f2h(acc[mi][ni][1]);
                v.z = f2h(acc[mi][ni][2]);
                v.w = f2h(acc[mi][ni][3]);
                *(u16x4v*)(Vt + ((size_t)bb * DIM + col) * SEQ + ss) = v;
            }
        }
    } else {
#pragma unroll
        for (int mi = 0; mi < 4; ++mi)
#pragma unroll
            for (int ni = 0; ni < 4; ++ni) {
                const int col = n0 + wcol + ni * 16 + c;
#pragma unroll
                for (int r = 0; r < 4; ++r) {
                    const int row = m0 + wrow + mi * 16 + q * 4 + r;
                    Yf[(size_t)row * DIM + col] = f2h(acc[mi][ni][r]);
                }
            }
    }
}

// ---------------------------------------------------------------------------
// Scores GEMM: S = Yf Xf^T * SCALE, fp16 out, scores==0 masked to 0xFC00 on
// the f32 accumulator. 1-D grid 544 = 8 XCD chunks x 68 consecutive
// triangular-t blocks (bijective): panel reuse stays within one L2.
// ---------------------------------------------------------------------------
__global__ __launch_bounds__(256) void scores_gemm1b(
    const unsigned short* __restrict__ Q, const unsigned short* __restrict__ K,
    unsigned short* __restrict__ S)
{
    __shared__ __attribute__((aligned(16))) unsigned short Ah[128 * 64];
    __shared__ __attribute__((aligned(16))) unsigned short Bh[128 * 64];
    const int flat = blockIdx.x;               // 0..543
    const int wg = (flat & 7) * 68 + (flat >> 3);  // XCD-chunked, bijective
    const int b = wg / 136;
    const int t = wg - b * 136;                // 0..135 triangular index
    int ti = (int)((__builtin_sqrtf(8.f * t + 1.f) - 1.f) * 0.5f);
    while ((ti + 1) * (ti + 2) / 2 <= t) ++ti;
    while (ti * (ti + 1) / 2 > t) --ti;
    const int tj = t - ti * (ti + 1) / 2;
    const int i0 = ti * 128, j0 = tj * 128;
    const unsigned short* Qb = Q + (size_t)b * SEQ * DIM;
    const unsigned short* Kb = K + (size_t)b * SEQ * DIM;
    unsigned short* Sb = S + (size_t)b * SEQ * SEQ;
    const int tid = threadIdx.x;
    const int w = tid >> 6, lane = tid & 63, q = lane >> 4, c = lane & 15;
    const int wrow = (w >> 1) * 64, wcol = (w & 1) * 64;
    const int g8 = lane >> 3;
    const int cu = (lane & 7) ^ g8;
    const int srow = w * 8 + g8;
    const int scol = cu * 8;
    unsigned short* lA = Ah + w * 512;
    unsigned short* lB = Bh + w * 512;
    const int c7 = c & 7;

    f32x4 acc[4][4];
#pragma unroll
    for (int a = 0; a < 4; ++a)
#pragma unroll
        for (int bq = 0; bq < 4; ++bq) acc[a][bq] = (f32x4){0.f, 0.f, 0.f, 0.f};

    for (int k0 = 0; k0 < DIM; k0 += 64) {
        __syncthreads();
        {
            const size_t ga = (size_t)(i0 + srow) * DIM + k0 + scol;
            const size_t gb = (size_t)(j0 + srow) * DIM + k0 + scol;
#pragma unroll
            for (int j = 0; j < 4; ++j) {
                gld_lds16(Qb + ga + (size_t)(j * 32) * DIM, lA + j * 2048);
                gld_lds16(Kb + gb + (size_t)(j * 32) * DIM, lB + j * 2048);
            }
        }
        __syncthreads();
#pragma unroll
        for (int kk = 0; kk < 2; ++kk) {
            f16x8 ah[4], bh[4];
#pragma unroll
            for (int mi = 0; mi < 4; ++mi)
                ah[mi] = ldsld(Ah + (wrow + mi * 16 + c) * 64 + (((kk << 2) + q) ^ c7) * 8);
#pragma unroll
            for (int ni = 0; ni < 4; ++ni)
                bh[ni] = ldsld(Bh + (wcol + ni * 16 + c) * 64 + (((kk << 2) + q) ^ c7) * 8);
#pragma unroll
            for (int mi = 0; mi < 4; ++mi)
#pragma unroll
                for (int ni = 0; ni < 4; ++ni)
                    acc[mi][ni] = __builtin_amdgcn_mfma_f32_16x16x32_f16(ah[mi], bh[ni], acc[mi][ni], 0, 0, 0);
        }
    }
#pragma unroll
    for (int mi = 0; mi < 4; ++mi)
#pragma unroll
        for (int ni = 0; ni < 4; ++ni) {
            const int col = j0 + wcol + ni * 16 + c;
#pragma unroll
            for (int r = 0; r < 4; ++r) {
                const int row = i0 + wrow + mi * 16 + q * 4 + r;
                const float sc = acc[mi][ni][r] * 0.03125f;
                Sb[(size_t)row * SEQ + col] =
                    (sc == 0.f) ? (unsigned short)0xFC00u : f2h(sc);
            }
        }
}

// ---------------------------------------------------------------------------
// Row-wise masked softmax: fp16 S -> fp16 P. j > i masked; scores==0 already
// -inf. Skip loads beyond i, skip writes beyond rowtile end. Grid (SEQ, BATCH).
// ---------------------------------------------------------------------------
__global__ __launch_bounds__(256) void softmax_row_b(
    const unsigned short* __restrict__ S, unsigned short* __restrict__ P)
{
    const int i = blockIdx.x, t = threadIdx.x;
    const size_t ro = ((size_t)blockIdx.y * SEQ + i) * SEQ;
    const int wid = t >> 6, lane = t & 63;
    __shared__ float redm[4], reds[4];
    const int j0 = t * 8;
    const int rti = (i & ~127) + 128;        // pv reads cols < rti only
    float sv[8];
    float mx = -__builtin_inff();
    if (j0 <= i) {
        u16x8v raw = *(const u16x8v*)(S + ro + j0);
#pragma unroll
        for (int u = 0; u < 8; ++u) {
            float s = (j0 + u <= i) ? h2f(raw[u]) : -__builtin_inff();
            sv[u] = s;
            mx = fmaxf(mx, s);
        }
    } else {
#pragma unroll
        for (int u = 0; u < 8; ++u) sv[u] = -__builtin_inff();
    }
#pragma unroll
    for (int off = 1; off < 64; off <<= 1) mx = fmaxf(mx, __shfl_xor(mx, off));
    if (lane == 0) redm[wid] = mx;
    __syncthreads();
    const float M = fmaxf(fmaxf(redm[0], redm[1]), fmaxf(redm[2], redm[3]));
    float sum = 0.f;
#pragma unroll
    for (int u = 0; u < 8; ++u) {
        float e = __expf(sv[u] - M);
        sv[u] = e;
        sum += e;
    }
#pragma unroll
    for (int off = 1; off < 64; off <<= 1) sum += __shfl_xor(sum, off);
    if (lane == 0) reds[wid] = sum;
    __syncthreads();
    const float rinv = 1.f / (reds[0] + reds[1] + reds[2] + reds[3]);
    if (j0 < rti) {
        u16x8v o;
#pragma unroll
        for (int u = 0; u < 8; ++u) o[u] = f2h(sv[u] * rinv);
        *(u16x8v*)(P + ro + j0) = o;
    }
}

// ---------------------------------------------------------------------------
// out = P @ V via Vt (NT MFMA, fp16), fp32 store. 128x128 tile, BK=64
// swizzled; k-loop truncated at causal bound. IN-BLOCK TILE PAIRING: each
// block serially computes tiles i0t = x and i0t = 15-x (same d0, b) ->
// constant (2x+2)+(2(15-x)+2) = 34 K-steps per block, 256 blocks = 1/CU.
// Robust balance: no atomics, no extra traffic, no dispatch assumptions
// (r3 split-K atomics and r5 dispatch-pairing both failed to pay).
// ---------------------------------------------------------------------------
__global__ __launch_bounds__(256) void pv_gemm(
    const unsigned short* __restrict__ Pm, const unsigned short* __restrict__ Vt,
    float* __restrict__ Out)
{
    __shared__ __attribute__((aligned(16))) unsigned short Ps[128 * 64];
    __shared__ __attribute__((aligned(16))) unsigned short Vs[128 * 64];
    const int xp = blockIdx.x;               // 0..7 pair index
    const int d0 = blockIdx.y * 128, b = blockIdx.z;
    const int tid = threadIdx.x;
    const int w = tid >> 6, lane = tid & 63, q = lane >> 4, c = lane & 15;
    const int wrow = (w >> 1) * 64, wcol = (w & 1) * 64;
    const int g8 = lane >> 3;
    const int cu = (lane & 7) ^ g8;
    const int srow = w * 8 + g8;
    const int scol = cu * 8;
    unsigned short* lA = Ps + w * 512;
    unsigned short* lB = Vs + w * 512;
    const int c7 = c & 7;

    for (int which = 0; which < 2; ++which) {
        const int i0t = which ? 15 - xp : xp;
        const int i0 = i0t * 128;
        const int njs = 2 * i0t + 2;         // covers cols < i0+128

        f32x4 acc[4][4];
#pragma unroll
        for (int a = 0; a < 4; ++a)
#pragma unroll
            for (int bq = 0; bq < 4; ++bq) acc[a][bq] = (f32x4){0.f, 0.f, 0.f, 0.f};

        for (int ks = 0; ks < njs; ++ks) {
            const int j0 = ks * 64;
            __syncthreads();
            {
                const size_t gpa = ((size_t)b * SEQ + i0 + srow) * SEQ + j0 + scol;
                const size_t gva = ((size_t)b * DIM + d0 + srow) * SEQ + j0 + scol;
#pragma unroll
                for (int j = 0; j < 4; ++j) {
                    gld_lds16(Pm + gpa + (size_t)(j * 32) * SEQ, lA + j * 2048);
                    gld_lds16(Vt + gva + (size_t)(j * 32) * SEQ, lB + j * 2048);
                }
            }
            __syncthreads();
#pragma unroll
            for (int kk = 0; kk < 2; ++kk) {
                f16x8 ah[4], bh[4];
#pragma unroll
                for (int mi = 0; mi < 4; ++mi)
                    ah[mi] = ldsld(Ps + (wrow + mi * 16 + c) * 64 + (((kk << 2) + q) ^ c7) * 8);
#pragma unroll
                for (int ni = 0; ni < 4; ++ni)
                    bh[ni] = ldsld(Vs + (wcol + ni * 16 + c) * 64 + (((kk << 2) + q) ^ c7) * 8);
#pragma unroll
                for (int mi = 0; mi < 4; ++mi)
#pragma unroll
                    for (int ni = 0; ni < 4; ++ni)
                        acc[mi][ni] = __builtin_amdgcn_mfma_f32_16x16x32_f16(ah[mi], bh[ni], acc[mi][ni], 0, 0, 0);
            }
        }
#pragma unroll
        for (int mi = 0; mi < 4; ++mi)
#pragma unroll
            for (int ni = 0; ni < 4; ++ni) {
                const int dcol = d0 + wcol + ni * 16 + c;
#pragma unroll
                for (int r = 0; r < 4; ++r) {
                    const int i = i0 + wrow + mi * 16 + q * 4 + r;
                    Out[((size_t)b * SEQ + i) * DIM + dcol] = acc[mi][ni][r];
                }
            }
    }
}

extern "C" void kernel_launch(void* const* d_in, const int* in_sizes, int n_in,
                              void* d_out, int out_size, void* d_ws, size_t ws_size,
                              hipStream_t stream)
{
    (void)out_size; (void)ws_size;
    const float* X = nullptr;
    const float* Wv[3] = {nullptr, nullptr, nullptr};
    int nw = 0;
    for (int i = 0; i < n_in; ++i) {
        if (in_sizes[i] == (int)NBS)
            X = (const float*)d_in[i];
        else if (nw < 3)
            Wv[nw++] = (const float*)d_in[i];
    }

    unsigned short* ws = (unsigned short*)d_ws;
    unsigned short* Yf = ws;                 // 16 MB
    unsigned short* Vt = ws + 2 * NBS;       // 16 MB
    unsigned short* Xf = ws + 3 * NBS;       // consumed by yv + scores
    unsigned short* Pp = ws + 3 * NBS;       // P aliases Xf after scores (32 MB)
    unsigned short* Sb = ws + 5 * NBS;       // fp16 S, all batches (32 MB)
    unsigned short* Wf = ws + 7 * NBS;       // 6 MB (Wq,Wk,Wv fp16)
    unsigned short* Mtb = Wf + (size_t)3 * DIM * DIM;   // 2 MB
    unsigned short* WqT = Mtb + (size_t)DIM * DIM;      // 2 MB
    unsigned short* WkT = WqT + (size_t)DIM * DIM;      // 2 MB
    float* Out = (float*)d_out;

    // Wv[0]=WQ, Wv[1]=WK, Wv[2]=WV (input order).
    cvt_all<<<dim3(8192 + 3072 + 512), 256, 0, stream>>>(
        X, Wv[0], Wv[1], Wv[2], Xf, Wf, WqT, WkT);

    mt_gemm<<<dim3(8, 8), 256, 0, stream>>>(WkT, WqT, Mtb);

    yv_gemm<<<dim3(64, 8, 2), 256, 0, stream>>>(
        Xf, Mtb, Wf + (size_t)2 * DIM * DIM, Yf, Vt);

    scores_gemm1b<<<dim3(544), 256, 0, stream>>>(Yf, Xf, Sb);
    softmax_row_b<<<dim3(SEQ, BATCH), 256, 0, stream>>>(Sb, Pp);

    pv_gemm<<<dim3(8, 8, BATCH), 256, 0, stream>>>(Pp, Vt, Out);
}

// Round 10
// 241.006 us; speedup vs baseline: 1.0214x; 1.0214x over previous
//
#include <hip/hip_runtime.h>

typedef _Float16 f16x8 __attribute__((ext_vector_type(8)));
typedef unsigned short u16x8v __attribute__((ext_vector_type(8)));
typedef unsigned short u16x4v __attribute__((ext_vector_type(4)));
typedef float f32x4 __attribute__((ext_vector_type(4)));

constexpr int SEQ = 2048;
constexpr int DIM = 1024;
constexpr int BATCH = 4;
constexpr size_t NBS = (size_t)BATCH * SEQ * DIM;  // 8388608

static __device__ __forceinline__ unsigned short f2h(float f) {
    return __builtin_bit_cast(unsigned short, (_Float16)f);  // RNE
}
static __device__ __forceinline__ float h2f(unsigned short u) {
    return (float)__builtin_bit_cast(_Float16, u);
}
static __device__ __forceinline__ f16x8 ldsld(const unsigned short* p) {
    return __builtin_bit_cast(f16x8, *(const u16x8v*)p);
}
// Async global->LDS, 16B/lane. LDS dest = wave-uniform base + lane*16B.
static __device__ __forceinline__ void gld_lds16(const unsigned short* g, unsigned short* l) {
    __builtin_amdgcn_global_load_lds(
        (const __attribute__((address_space(1))) void*)g,
        (__attribute__((address_space(3))) void*)l, 16, 0, 0);
}

// ---------------------------------------------------------------------------
// cvt + transpose, ONE launch:
//   [0,8192):            X fp32 -> fp16.
//   [8192,8192+3072):    Wq,Wk,Wv fp32 -> fp16 (k-major, as input).
//   [11264,11264+512):   WqT/WkT fp32 -> fp16 TRANSPOSED [e][k] (64x64 LDS
//                        tiles) so mt_gemm can be a standard NT GEMM.
// ---------------------------------------------------------------------------
__global__ __launch_bounds__(256) void cvt_all(
    const float* __restrict__ X,
    const float* __restrict__ W0, const float* __restrict__ W1,
    const float* __restrict__ W2,
    unsigned short* __restrict__ Xf, unsigned short* __restrict__ Wf,
    unsigned short* __restrict__ WqT, unsigned short* __restrict__ WkT)
{
    __shared__ __attribute__((aligned(16))) unsigned short T[64][72];  // 144B rows: 16B-aligned
    const int b = blockIdx.x;
    const int t = threadIdx.x;
    if (b < 11264) {
        const float* src;
        unsigned short* dst;
        int i;
        if (b < 8192) {
            src = X; dst = Xf;
            i = b * 256 + t;
        } else {
            const int wb = b - 8192;
            const int z = wb >> 10;              // 1024 blocks per weight
            src = (z == 0) ? W0 : (z == 1) ? W1 : W2;
            dst = Wf + (size_t)z * DIM * DIM;
            i = (wb & 1023) * 256 + t;
        }
        float4 f = ((const float4*)src)[i];
        u16x4v h;
        h.x = f2h(f.x); h.y = f2h(f.y); h.z = f2h(f.z); h.w = f2h(f.w);
        ((u16x4v*)dst)[i] = h;
        return;
    }
    // ---- transpose blocks ----
    const int tb = b - 11264;                    // 0..511
    const float* src = (tb < 256) ? W0 : W1;     // Wq then Wk
    unsigned short* dst = (tb < 256) ? WqT : WkT;
    const int tile = tb & 255;
    const int tk = (tile >> 4) * 64;             // k tile base
    const int te = (tile & 15) * 64;             // e tile base
    const int cu = t & 15, kr4 = t >> 4;         // read: 16 rows/pass, 4 cols/thread
#pragma unroll
    for (int p = 0; p < 4; ++p) {
        const int k = p * 16 + kr4;
        float4 v = *(const float4*)(src + (size_t)(tk + k) * DIM + te + cu * 4);
        T[cu * 4 + 0][k] = f2h(v.x);
        T[cu * 4 + 1][k] = f2h(v.y);
        T[cu * 4 + 2][k] = f2h(v.z);
        T[cu * 4 + 3][k] = f2h(v.w);
    }
    __syncthreads();
    const int un = t & 7, er = t >> 3;           // write: 32 rows/pass, 16B/thread
#pragma unroll
    for (int p = 0; p < 2; ++p) {
        const int e = p * 32 + er;
        *(u16x8v*)(dst + (size_t)(te + e) * DIM + tk + un * 8) =
            *(const u16x8v*)&T[e][un * 8];
    }
}

// ---------------------------------------------------------------------------
// Mt[e'][e] = sum_k Wk[k][e'] Wq[k][e] as a standard NT GEMM on the
// TRANSPOSED copies: A = WkT [e'][k], B = WqT [e][k]. Same swizzled BK=64
// structure as yv_gemm. Grid (8,8).
// ---------------------------------------------------------------------------
__global__ __launch_bounds__(256) void mt_gemm(
    const unsigned short* __restrict__ WkTp, const unsigned short* __restrict__ WqTp,
    unsigned short* __restrict__ Mt)
{
    __shared__ __attribute__((aligned(16))) unsigned short Ah[128 * 64];
    __shared__ __attribute__((aligned(16))) unsigned short Bh[128 * 64];
    const int m0 = blockIdx.x * 128, n0 = blockIdx.y * 128;  // e' rows, e cols
    const int tid = threadIdx.x;
    const int w = tid >> 6, lane = tid & 63, q = lane >> 4, c = lane & 15;
    const int wrow = (w >> 1) * 64, wcol = (w & 1) * 64;
    const int g8 = lane >> 3;
    const int cu = (lane & 7) ^ g8;
    const int srow = w * 8 + g8;
    const int scol = cu * 8;
    unsigned short* lA = Ah + w * 512;
    unsigned short* lB = Bh + w * 512;
    const int c7 = c & 7;

    f32x4 acc[4][4];
#pragma unroll
    for (int a = 0; a < 4; ++a)
#pragma unroll
        for (int bq = 0; bq < 4; ++bq) acc[a][bq] = (f32x4){0.f, 0.f, 0.f, 0.f};

    for (int k0 = 0; k0 < DIM; k0 += 64) {
        __syncthreads();
        {
            const size_t ga = (size_t)(m0 + srow) * DIM + k0 + scol;
            const size_t gb = (size_t)(n0 + srow) * DIM + k0 + scol;
#pragma unroll
            for (int j = 0; j < 4; ++j) {
                gld_lds16(WkTp + ga + (size_t)(j * 32) * DIM, lA + j * 2048);
                gld_lds16(WqTp + gb + (size_t)(j * 32) * DIM, lB + j * 2048);
            }
        }
        __syncthreads();
#pragma unroll
        for (int kk = 0; kk < 2; ++kk) {
            f16x8 af[4], bf[4];
#pragma unroll
            for (int mi = 0; mi < 4; ++mi)
                af[mi] = ldsld(Ah + (wrow + mi * 16 + c) * 64 + (((kk << 2) + q) ^ c7) * 8);
#pragma unroll
            for (int ni = 0; ni < 4; ++ni)
                bf[ni] = ldsld(Bh + (wcol + ni * 16 + c) * 64 + (((kk << 2) + q) ^ c7) * 8);
#pragma unroll
            for (int mi = 0; mi < 4; ++mi)
#pragma unroll
                for (int ni = 0; ni < 4; ++ni)
                    acc[mi][ni] = __builtin_amdgcn_mfma_f32_16x16x32_f16(af[mi], bf[ni], acc[mi][ni], 0, 0, 0);
        }
    }
#pragma unroll
    for (int mi = 0; mi < 4; ++mi)
#pragma unroll
        for (int ni = 0; ni < 4; ++ni) {
            const int col = n0 + wcol + ni * 16 + c;
#pragma unroll
            for (int r = 0; r < 4; ++r) {
                const int row = m0 + wrow + mi * 16 + q * 4 + r;
                Mt[(size_t)row * DIM + col] = f2h(acc[mi][ni][r]);
            }
        }
}

// ---------------------------------------------------------------------------
// Fused Y/V projection, fp16 MFMA. z=0: Y = NT(Xf, Mt); z=1: V = NT(Xf, Wvf)
// stored transposed Vt[b][d][s]. 128x128 tile, BK=64 swizzled, m fastest.
// ---------------------------------------------------------------------------
__global__ __launch_bounds__(256) void yv_gemm(
    const unsigned short* __restrict__ Xf, const unsigned short* __restrict__ Mt,
    const unsigned short* __restrict__ Wvf,
    unsigned short* __restrict__ Yf, unsigned short* __restrict__ Vt)
{
    __shared__ __attribute__((aligned(16))) unsigned short Ah[128 * 64];
    __shared__ __attribute__((aligned(16))) unsigned short Bh[128 * 64];
    const int m0 = blockIdx.x * 128, n0 = blockIdx.y * 128, z = blockIdx.z;
    const unsigned short* Wz = z ? Wvf : Mt;
    const int tid = threadIdx.x;
    const int w = tid >> 6, lane = tid & 63, q = lane >> 4, c = lane & 15;
    const int wrow = (w >> 1) * 64, wcol = (w & 1) * 64;
    const int g8 = lane >> 3;
    const int cu = (lane & 7) ^ g8;
    const int srow = w * 8 + g8;
    const int scol = cu * 8;
    unsigned short* lA = Ah + w * 512;
    unsigned short* lB = Bh + w * 512;
    const int c7 = c & 7;

    f32x4 acc[4][4];
#pragma unroll
    for (int a = 0; a < 4; ++a)
#pragma unroll
        for (int b = 0; b < 4; ++b) acc[a][b] = (f32x4){0.f, 0.f, 0.f, 0.f};

    for (int k0 = 0; k0 < DIM; k0 += 64) {
        __syncthreads();
        {
            const size_t ga = (size_t)(m0 + srow) * DIM + k0 + scol;
            const size_t gb = (size_t)(n0 + srow) * DIM + k0 + scol;
#pragma unroll
            for (int j = 0; j < 4; ++j) {
                gld_lds16(Xf + ga + (size_t)(j * 32) * DIM, lA + j * 2048);
                gld_lds16(Wz + gb + (size_t)(j * 32) * DIM, lB + j * 2048);
            }
        }
        __syncthreads();
#pragma unroll
        for (int kk = 0; kk < 2; ++kk) {
            f16x8 ah[4], bh[4];
#pragma unroll
            for (int mi = 0; mi < 4; ++mi)
                ah[mi] = ldsld(Ah + (wrow + mi * 16 + c) * 64 + (((kk << 2) + q) ^ c7) * 8);
#pragma unroll
            for (int ni = 0; ni < 4; ++ni)
                bh[ni] = ldsld(Bh + (wcol + ni * 16 + c) * 64 + (((kk << 2) + q) ^ c7) * 8);
#pragma unroll
            for (int mi = 0; mi < 4; ++mi)
#pragma unroll
                for (int ni = 0; ni < 4; ++ni)
                    acc[mi][ni] = __builtin_amdgcn_mfma_f32_16x16x32_f16(ah[mi], bh[ni], acc[mi][ni], 0, 0, 0);
        }
    }

    if (z == 1) {
        // V: store transposed Vt[b][d][s], fp16.
#pragma unroll
        for (int mi = 0; mi < 4; ++mi) {
            const int mg = m0 + wrow + mi * 16 + q * 4;
            const int bb = mg >> 11, ss = mg & (SEQ - 1);
#pragma unroll
            for (int ni = 0; ni < 4; ++ni) {
                const int col = n0 + wcol + ni * 16 + c;
                u16x4v v;
                v.x = f2h(acc[mi][ni][0]);
                v.y = f2h(acc[mi][ni][1]);
                v.z = f2h(acc[mi][ni][2]);
                v.w = f2h(acc[mi][ni][3]);
                *(u16x4v*)(Vt + ((size_t)bb * DIM + col) * SEQ + ss) = v;
            }
        }
    } else {
#pragma unroll
        for (int mi = 0; mi < 4; ++mi)
#pragma unroll
            for (int ni = 0; ni < 4; ++ni) {
                const int col = n0 + wcol + ni * 16 + c;
#pragma unroll
                for (int r = 0; r < 4; ++r) {
                    const int row = m0 + wrow + mi * 16 + q * 4 + r;
                    Yf[(size_t)row * DIM + col] = f2h(acc[mi][ni][r]);
                }
            }
    }
}

// ---------------------------------------------------------------------------
// Scores GEMM: S = Yf Xf^T * SCALE, fp16 out, scores==0 masked to 0xFC00 on
// the f32 accumulator. 1-D grid 544 = 8 XCD chunks x 68 consecutive
// triangular-t blocks (bijective): panel reuse stays within one L2.
// ---------------------------------------------------------------------------
__global__ __launch_bounds__(256) void scores_gemm1b(
    const unsigned short* __restrict__ Q, const unsigned short* __restrict__ K,
    unsigned short* __restrict__ S)
{
    __shared__ __attribute__((aligned(16))) unsigned short Ah[128 * 64];
    __shared__ __attribute__((aligned(16))) unsigned short Bh[128 * 64];
    const int flat = blockIdx.x;               // 0..543
    const int wg = (flat & 7) * 68 + (flat >> 3);  // XCD-chunked, bijective
    const int b = wg / 136;
    const int t = wg - b * 136;                // 0..135 triangular index
    int ti = (int)((__builtin_sqrtf(8.f * t + 1.f) - 1.f) * 0.5f);
    while ((ti + 1) * (ti + 2) / 2 <= t) ++ti;
    while (ti * (ti + 1) / 2 > t) --ti;
    const int tj = t - ti * (ti + 1) / 2;
    const int i0 = ti * 128, j0 = tj * 128;
    const unsigned short* Qb = Q + (size_t)b * SEQ * DIM;
    const unsigned short* Kb = K + (size_t)b * SEQ * DIM;
    unsigned short* Sb = S + (size_t)b * SEQ * SEQ;
    const int tid = threadIdx.x;
    const int w = tid >> 6, lane = tid & 63, q = lane >> 4, c = lane & 15;
    const int wrow = (w >> 1) * 64, wcol = (w & 1) * 64;
    const int g8 = lane >> 3;
    const int cu = (lane & 7) ^ g8;
    const int srow = w * 8 + g8;
    const int scol = cu * 8;
    unsigned short* lA = Ah + w * 512;
    unsigned short* lB = Bh + w * 512;
    const int c7 = c & 7;

    f32x4 acc[4][4];
#pragma unroll
    for (int a = 0; a < 4; ++a)
#pragma unroll
        for (int bq = 0; bq < 4; ++bq) acc[a][bq] = (f32x4){0.f, 0.f, 0.f, 0.f};

    for (int k0 = 0; k0 < DIM; k0 += 64) {
        __syncthreads();
        {
            const size_t ga = (size_t)(i0 + srow) * DIM + k0 + scol;
            const size_t gb = (size_t)(j0 + srow) * DIM + k0 + scol;
#pragma unroll
            for (int j = 0; j < 4; ++j) {
                gld_lds16(Qb + ga + (size_t)(j * 32) * DIM, lA + j * 2048);
                gld_lds16(Kb + gb + (size_t)(j * 32) * DIM, lB + j * 2048);
            }
        }
        __syncthreads();
#pragma unroll
        for (int kk = 0; kk < 2; ++kk) {
            f16x8 ah[4], bh[4];
#pragma unroll
            for (int mi = 0; mi < 4; ++mi)
                ah[mi] = ldsld(Ah + (wrow + mi * 16 + c) * 64 + (((kk << 2) + q) ^ c7) * 8);
#pragma unroll
            for (int ni = 0; ni < 4; ++ni)
                bh[ni] = ldsld(Bh + (wcol + ni * 16 + c) * 64 + (((kk << 2) + q) ^ c7) * 8);
#pragma unroll
            for (int mi = 0; mi < 4; ++mi)
#pragma unroll
                for (int ni = 0; ni < 4; ++ni)
                    acc[mi][ni] = __builtin_amdgcn_mfma_f32_16x16x32_f16(ah[mi], bh[ni], acc[mi][ni], 0, 0, 0);
        }
    }
#pragma unroll
    for (int mi = 0; mi < 4; ++mi)
#pragma unroll
        for (int ni = 0; ni < 4; ++ni) {
            const int col = j0 + wcol + ni * 16 + c;
#pragma unroll
            for (int r = 0; r < 4; ++r) {
                const int row = i0 + wrow + mi * 16 + q * 4 + r;
                const float sc = acc[mi][ni][r] * 0.03125f;
                Sb[(size_t)row * SEQ + col] =
                    (sc == 0.f) ? (unsigned short)0xFC00u : f2h(sc);
            }
        }
}

// ---------------------------------------------------------------------------
// Row-wise masked softmax: fp16 S -> fp16 P. j > i masked; scores==0 already
// -inf. Skip loads beyond i, skip writes beyond rowtile end. Grid (SEQ, BATCH).
// ---------------------------------------------------------------------------
__global__ __launch_bounds__(256) void softmax_row_b(
    const unsigned short* __restrict__ S, unsigned short* __restrict__ P)
{
    const int i = blockIdx.x, t = threadIdx.x;
    const size_t ro = ((size_t)blockIdx.y * SEQ + i) * SEQ;
    const int wid = t >> 6, lane = t & 63;
    __shared__ float redm[4], reds[4];
    const int j0 = t * 8;
    const int rti = (i & ~127) + 128;        // pv reads cols < rti only
    float sv[8];
    float mx = -__builtin_inff();
    if (j0 <= i) {
        u16x8v raw = *(const u16x8v*)(S + ro + j0);
#pragma unroll
        for (int u = 0; u < 8; ++u) {
            float s = (j0 + u <= i) ? h2f(raw[u]) : -__builtin_inff();
            sv[u] = s;
            mx = fmaxf(mx, s);
        }
    } else {
#pragma unroll
        for (int u = 0; u < 8; ++u) sv[u] = -__builtin_inff();
    }
#pragma unroll
    for (int off = 1; off < 64; off <<= 1) mx = fmaxf(mx, __shfl_xor(mx, off));
    if (lane == 0) redm[wid] = mx;
    __syncthreads();
    const float M = fmaxf(fmaxf(redm[0], redm[1]), fmaxf(redm[2], redm[3]));
    float sum = 0.f;
#pragma unroll
    for (int u = 0; u < 8; ++u) {
        float e = __expf(sv[u] - M);
        sv[u] = e;
        sum += e;
    }
#pragma unroll
    for (int off = 1; off < 64; off <<= 1) sum += __shfl_xor(sum, off);
    if (lane == 0) reds[wid] = sum;
    __syncthreads();
    const float rinv = 1.f / (reds[0] + reds[1] + reds[2] + reds[3]);
    if (j0 < rti) {
        u16x8v o;
#pragma unroll
        for (int u = 0; u < 8; ++u) o[u] = f2h(sv[u] * rinv);
        *(u16x8v*)(P + ro + j0) = o;
    }
}

// ---------------------------------------------------------------------------
// out = P @ V via Vt (NT MFMA, fp16), fp32 store. 128x128 tile, BK=64
// swizzled; k-loop truncated at causal bound. 512 blocks (2/CU: r9's 1/CU
// pairing killed barrier overlap -- do not reintroduce). XCD-CHUNKED 1-D
// grid: XCD x owns wg [x*64, x*64+64) = 4 complete (b,d0) groups x 16 i0t
// tiles, so the group's 512 KB Vt panel + batch P stay L2-resident (same
// fix that paid for scores in r8). Per-XCD work exactly equal (272 steps
// per group).
// ---------------------------------------------------------------------------
__global__ __launch_bounds__(256) void pv_gemm(
    const unsigned short* __restrict__ Pm, const unsigned short* __restrict__ Vt,
    float* __restrict__ Out)
{
    __shared__ __attribute__((aligned(16))) unsigned short Ps[128 * 64];
    __shared__ __attribute__((aligned(16))) unsigned short Vs[128 * 64];
    const int flat = blockIdx.x;             // 0..511
    const int wg = (flat & 7) * 64 + (flat >> 3);  // XCD-chunked, bijective
    const int i0t = wg & 15;
    const int grp = wg >> 4;                 // 0..31
    const int b = grp >> 3;
    const int d0 = (grp & 7) * 128;
    const int i0 = i0t * 128;
    const int tid = threadIdx.x;
    const int w = tid >> 6, lane = tid & 63, q = lane >> 4, c = lane & 15;
    const int wrow = (w >> 1) * 64, wcol = (w & 1) * 64;
    const int g8 = lane >> 3;
    const int cu = (lane & 7) ^ g8;
    const int srow = w * 8 + g8;
    const int scol = cu * 8;
    unsigned short* lA = Ps + w * 512;
    unsigned short* lB = Vs + w * 512;
    const int c7 = c & 7;

    f32x4 acc[4][4];
#pragma unroll
    for (int a = 0; a < 4; ++a)
#pragma unroll
        for (int bq = 0; bq < 4; ++bq) acc[a][bq] = (f32x4){0.f, 0.f, 0.f, 0.f};

    const int njs = 2 * i0t + 2;  // covers cols < i0+128

    for (int ks = 0; ks < njs; ++ks) {
        const int j0 = ks * 64;
        __syncthreads();
        {
            const size_t gpa = ((size_t)b * SEQ + i0 + srow) * SEQ + j0 + scol;
            const size_t gva = ((size_t)b * DIM + d0 + srow) * SEQ + j0 + scol;
#pragma unroll
            for (int j = 0; j < 4; ++j) {
                gld_lds16(Pm + gpa + (size_t)(j * 32) * SEQ, lA + j * 2048);
                gld_lds16(Vt + gva + (size_t)(j * 32) * SEQ, lB + j * 2048);
            }
        }
        __syncthreads();
#pragma unroll
        for (int kk = 0; kk < 2; ++kk) {
            f16x8 ah[4], bh[4];
#pragma unroll
            for (int mi = 0; mi < 4; ++mi)
                ah[mi] = ldsld(Ps + (wrow + mi * 16 + c) * 64 + (((kk << 2) + q) ^ c7) * 8);
#pragma unroll
            for (int ni = 0; ni < 4; ++ni)
                bh[ni] = ldsld(Vs + (wcol + ni * 16 + c) * 64 + (((kk << 2) + q) ^ c7) * 8);
#pragma unroll
            for (int mi = 0; mi < 4; ++mi)
#pragma unroll
                for (int ni = 0; ni < 4; ++ni)
                    acc[mi][ni] = __builtin_amdgcn_mfma_f32_16x16x32_f16(ah[mi], bh[ni], acc[mi][ni], 0, 0, 0);
        }
    }
#pragma unroll
    for (int mi = 0; mi < 4; ++mi)
#pragma unroll
        for (int ni = 0; ni < 4; ++ni) {
            const int dcol = d0 + wcol + ni * 16 + c;
#pragma unroll
            for (int r = 0; r < 4; ++r) {
                const int i = i0 + wrow + mi * 16 + q * 4 + r;
                Out[((size_t)b * SEQ + i) * DIM + dcol] = acc[mi][ni][r];
            }
        }
}

extern "C" void kernel_launch(void* const* d_in, const int* in_sizes, int n_in,
                              void* d_out, int out_size, void* d_ws, size_t ws_size,
                              hipStream_t stream)
{
    (void)out_size; (void)ws_size;
    const float* X = nullptr;
    const float* Wv[3] = {nullptr, nullptr, nullptr};
    int nw = 0;
    for (int i = 0; i < n_in; ++i) {
        if (in_sizes[i] == (int)NBS)
            X = (const float*)d_in[i];
        else if (nw < 3)
            Wv[nw++] = (const float*)d_in[i];
    }

    unsigned short* ws = (unsigned short*)d_ws;
    unsigned short* Yf = ws;                 // 16 MB
    unsigned short* Vt = ws + 2 * NBS;       // 16 MB
    unsigned short* Xf = ws + 3 * NBS;       // consumed by yv + scores
    unsigned short* Pp = ws + 3 * NBS;       // P aliases Xf after scores (32 MB)
    unsigned short* Sb = ws + 5 * NBS;       // fp16 S, all batches (32 MB)
    unsigned short* Wf = ws + 7 * NBS;       // 6 MB (Wq,Wk,Wv fp16)
    unsigned short* Mtb = Wf + (size_t)3 * DIM * DIM;   // 2 MB
    unsigned short* WqT = Mtb + (size_t)DIM * DIM;      // 2 MB
    unsigned short* WkT = WqT + (size_t)DIM * DIM;      // 2 MB
    float* Out = (float*)d_out;

    // Wv[0]=WQ, Wv[1]=WK, Wv[2]=WV (input order).
    cvt_all<<<dim3(8192 + 3072 + 512), 256, 0, stream>>>(
        X, Wv[0], Wv[1], Wv[2], Xf, Wf, WqT, WkT);

    mt_gemm<<<dim3(8, 8), 256, 0, stream>>>(WkT, WqT, Mtb);

    yv_gemm<<<dim3(64, 8, 2), 256, 0, stream>>>(
        Xf, Mtb, Wf + (size_t)2 * DIM * DIM, Yf, Vt);

    scores_gemm1b<<<dim3(544), 256, 0, stream>>>(Yf, Xf, Sb);
    softmax_row_b<<<dim3(SEQ, BATCH), 256, 0, stream>>>(Sb, Pp);

    pv_gemm<<<dim3(512), 256, 0, stream>>>(Pp, Vt, Out);
}

// Round 11
// 235.621 us; speedup vs baseline: 1.0447x; 1.0229x over previous
//
#include <hip/hip_runtime.h>

typedef _Float16 f16x8 __attribute__((ext_vector_type(8)));
typedef unsigned short u16x8v __attribute__((ext_vector_type(8)));
typedef unsigned short u16x4v __attribute__((ext_vector_type(4)));
typedef float f32x4 __attribute__((ext_vector_type(4)));

constexpr int SEQ = 2048;
constexpr int DIM = 1024;
constexpr int BATCH = 4;
constexpr size_t NBS = (size_t)BATCH * SEQ * DIM;  // 8388608

static __device__ __forceinline__ unsigned short f2h(float f) {
    return __builtin_bit_cast(unsigned short, (_Float16)f);  // RNE
}
static __device__ __forceinline__ float h2f(unsigned short u) {
    return (float)__builtin_bit_cast(_Float16, u);
}
static __device__ __forceinline__ f16x8 ldsld(const unsigned short* p) {
    return __builtin_bit_cast(f16x8, *(const u16x8v*)p);
}
// Async global->LDS, 16B/lane. LDS dest = wave-uniform base + lane*16B.
static __device__ __forceinline__ void gld_lds16(const unsigned short* g, unsigned short* l) {
    __builtin_amdgcn_global_load_lds(
        (const __attribute__((address_space(1))) void*)g,
        (__attribute__((address_space(3))) void*)l, 16, 0, 0);
}
// Barrier that is also a compiler memory fence (raw s_barrier is NOT a
// motion fence in LLVM; the "memory" clobber blocks LDS-read/stage hoisting
// across it without pinning VALU/MFMA scheduling).
static __device__ __forceinline__ void barrier_mf() {
    asm volatile("s_barrier" ::: "memory");
}

// ---------------------------------------------------------------------------
// cvt + transpose, ONE launch:
//   [0,8192):            X fp32 -> fp16.
//   [8192,8192+3072):    Wq,Wk,Wv fp32 -> fp16 (k-major, as input).
//   [11264,11264+512):   WqT/WkT fp32 -> fp16 TRANSPOSED [e][k].
// ---------------------------------------------------------------------------
__global__ __launch_bounds__(256) void cvt_all(
    const float* __restrict__ X,
    const float* __restrict__ W0, const float* __restrict__ W1,
    const float* __restrict__ W2,
    unsigned short* __restrict__ Xf, unsigned short* __restrict__ Wf,
    unsigned short* __restrict__ WqT, unsigned short* __restrict__ WkT)
{
    __shared__ __attribute__((aligned(16))) unsigned short T[64][72];
    const int b = blockIdx.x;
    const int t = threadIdx.x;
    if (b < 11264) {
        const float* src;
        unsigned short* dst;
        int i;
        if (b < 8192) {
            src = X; dst = Xf;
            i = b * 256 + t;
        } else {
            const int wb = b - 8192;
            const int z = wb >> 10;
            src = (z == 0) ? W0 : (z == 1) ? W1 : W2;
            dst = Wf + (size_t)z * DIM * DIM;
            i = (wb & 1023) * 256 + t;
        }
        float4 f = ((const float4*)src)[i];
        u16x4v h;
        h.x = f2h(f.x); h.y = f2h(f.y); h.z = f2h(f.z); h.w = f2h(f.w);
        ((u16x4v*)dst)[i] = h;
        return;
    }
    const int tb = b - 11264;
    const float* src = (tb < 256) ? W0 : W1;
    unsigned short* dst = (tb < 256) ? WqT : WkT;
    const int tile = tb & 255;
    const int tk = (tile >> 4) * 64;
    const int te = (tile & 15) * 64;
    const int cu = t & 15, kr4 = t >> 4;
#pragma unroll
    for (int p = 0; p < 4; ++p) {
        const int k = p * 16 + kr4;
        float4 v = *(const float4*)(src + (size_t)(tk + k) * DIM + te + cu * 4);
        T[cu * 4 + 0][k] = f2h(v.x);
        T[cu * 4 + 1][k] = f2h(v.y);
        T[cu * 4 + 2][k] = f2h(v.z);
        T[cu * 4 + 3][k] = f2h(v.w);
    }
    __syncthreads();
    const int un = t & 7, er = t >> 3;
#pragma unroll
    for (int p = 0; p < 2; ++p) {
        const int e = p * 32 + er;
        *(u16x8v*)(dst + (size_t)(te + e) * DIM + tk + un * 8) =
            *(const u16x8v*)&T[e][un * 8];
    }
}

// ---------------------------------------------------------------------------
// Mt[e'][e] = sum_k Wk[k][e'] Wq[k][e], NT GEMM on transposed copies.
// ---------------------------------------------------------------------------
__global__ __launch_bounds__(256) void mt_gemm(
    const unsigned short* __restrict__ WkTp, const unsigned short* __restrict__ WqTp,
    unsigned short* __restrict__ Mt)
{
    __shared__ __attribute__((aligned(16))) unsigned short Ah[128 * 64];
    __shared__ __attribute__((aligned(16))) unsigned short Bh[128 * 64];
    const int m0 = blockIdx.x * 128, n0 = blockIdx.y * 128;
    const int tid = threadIdx.x;
    const int w = tid >> 6, lane = tid & 63, q = lane >> 4, c = lane & 15;
    const int wrow = (w >> 1) * 64, wcol = (w & 1) * 64;
    const int g8 = lane >> 3;
    const int cu = (lane & 7) ^ g8;
    const int srow = w * 8 + g8;
    const int scol = cu * 8;
    unsigned short* lA = Ah + w * 512;
    unsigned short* lB = Bh + w * 512;
    const int c7 = c & 7;

    f32x4 acc[4][4];
#pragma unroll
    for (int a = 0; a < 4; ++a)
#pragma unroll
        for (int bq = 0; bq < 4; ++bq) acc[a][bq] = (f32x4){0.f, 0.f, 0.f, 0.f};

    for (int k0 = 0; k0 < DIM; k0 += 64) {
        __syncthreads();
        {
            const size_t ga = (size_t)(m0 + srow) * DIM + k0 + scol;
            const size_t gb = (size_t)(n0 + srow) * DIM + k0 + scol;
#pragma unroll
            for (int j = 0; j < 4; ++j) {
                gld_lds16(WkTp + ga + (size_t)(j * 32) * DIM, lA + j * 2048);
                gld_lds16(WqTp + gb + (size_t)(j * 32) * DIM, lB + j * 2048);
            }
        }
        __syncthreads();
#pragma unroll
        for (int kk = 0; kk < 2; ++kk) {
            f16x8 af[4], bf[4];
#pragma unroll
            for (int mi = 0; mi < 4; ++mi)
                af[mi] = ldsld(Ah + (wrow + mi * 16 + c) * 64 + (((kk << 2) + q) ^ c7) * 8);
#pragma unroll
            for (int ni = 0; ni < 4; ++ni)
                bf[ni] = ldsld(Bh + (wcol + ni * 16 + c) * 64 + (((kk << 2) + q) ^ c7) * 8);
#pragma unroll
            for (int mi = 0; mi < 4; ++mi)
#pragma unroll
                for (int ni = 0; ni < 4; ++ni)
                    acc[mi][ni] = __builtin_amdgcn_mfma_f32_16x16x32_f16(af[mi], bf[ni], acc[mi][ni], 0, 0, 0);
        }
    }
#pragma unroll
    for (int mi = 0; mi < 4; ++mi)
#pragma unroll
        for (int ni = 0; ni < 4; ++ni) {
            const int col = n0 + wcol + ni * 16 + c;
#pragma unroll
            for (int r = 0; r < 4; ++r) {
                const int row = m0 + wrow + mi * 16 + q * 4 + r;
                Mt[(size_t)row * DIM + col] = f2h(acc[mi][ni][r]);
            }
        }
}

// ---------------------------------------------------------------------------
// Y/V projection, 256x256 tile, 8-PHASE counted-vmcnt schedule (T3+T4+T5 on
// top of T2 swizzle; §5 template, m248: +29% at K=1024 vs 2-phase).
// 512 threads = 8 waves (2M x 4N), per-wave C = 128x64 (8x4 16x16 frags).
// LDS 128KB: buf0/buf1 x (A[256][64] + B[256][64]) fp16, unit-XOR swizzled.
// Per iteration: 2 K-tiles x 4 phases. Phase = {ds_read A-subtile (+all B at
// quadrant 0) ; stage ONE half-tile ; barrier ; setprio(1) 16 MFMA setprio(0);
// barrier}. Staging slots: ph0,1 -> (u+1).A ; ph2,3 -> (u+2).B ;
// ph4,5 -> (u+2).A ; ph6,7 -> (u+3).B — every stage is issued only after the
// target region's last reader passed a barrier. vmcnt(4) guards at ph0/ph4
// only (vmcnt(0) at the final second-half); loads stay in flight across
// barriers. All barriers are asm s_barrier with "memory" clobber.
// z=0: Y = NT(Xf, Mt); z=1: V = NT(Xf, Wvf), stored transposed Vt[b][d][s].
// ---------------------------------------------------------------------------
__global__ __launch_bounds__(512) void yv8_gemm(
    const unsigned short* __restrict__ Xf, const unsigned short* __restrict__ Mt,
    const unsigned short* __restrict__ Wvf,
    unsigned short* __restrict__ Yf, unsigned short* __restrict__ Vt)
{
    __shared__ __attribute__((aligned(16))) unsigned short L[65536];  // 128 KB
    unsigned short* A0 = L;
    unsigned short* B0 = L + 16384;
    unsigned short* A1 = L + 32768;
    unsigned short* B1 = L + 49152;

    const int m0 = blockIdx.x * 256, n0 = blockIdx.y * 256, z = blockIdx.z;
    const unsigned short* Bg = z ? Wvf : Mt;
    const int tid = threadIdx.x;
    const int w = tid >> 6, lane = tid & 63;
    const int wm = w >> 2, wn = w & 3;          // 2M x 4N waves
    const int c = lane & 15, q = lane >> 4, c7 = c & 7;
    const int sl8 = lane >> 3;                  // staging row-in-8
    const int gu = ((lane & 7) ^ sl8) * 8;      // inverse-swizzled col (shorts)

    // Stage one half-tile h (128 rows) of K-tile T of operand G into Lb.
    // 2 x gld_lds16 per thread; wave w covers rows h*128 + w*16 .. +16.
    auto stage = [&](const unsigned short* G, int roff, int T, unsigned short* Lb, int h) {
        const int rb0 = h * 128 + w * 16;
        const int kb = T * 64 + gu;
        gld_lds16(G + (size_t)(roff + rb0 + sl8) * DIM + kb, Lb + rb0 * 64 + lane * 8);
        gld_lds16(G + (size_t)(roff + rb0 + 8 + sl8) * DIM + kb, Lb + (rb0 + 8) * 64 + lane * 8);
    };
    auto rdA = [&](const unsigned short* LA, int fr, int kk) {
        const int row = wm * 128 + fr * 16 + c;
        return ldsld(LA + row * 64 + (((kk << 2) + q) ^ c7) * 8);
    };
    auto rdB = [&](const unsigned short* LB, int fb, int kk) {
        const int row = wn * 64 + fb * 16 + c;
        return ldsld(LB + row * 64 + (((kk << 2) + q) ^ c7) * 8);
    };

    f32x4 acc[8][4];
#pragma unroll
    for (int a = 0; a < 8; ++a)
#pragma unroll
        for (int bq = 0; bq < 4; ++bq) acc[a][bq] = (f32x4){0.f, 0.f, 0.f, 0.f};
    f16x8 bfr[4][2];

// One phase: quadrant p of a K-tile. LOADB: read all 8 B frags (phase 0).
#define PH(LAp, LBp, p, STAGES, LOADB)                                          \
    {                                                                           \
        if (LOADB) {                                                            \
            _Pragma("unroll") for (int fb = 0; fb < 4; ++fb) {                  \
                bfr[fb][0] = rdB(LBp, fb, 0);                                   \
                bfr[fb][1] = rdB(LBp, fb, 1);                                   \
            }                                                                   \
        }                                                                       \
        f16x8 a00 = rdA(LAp, 2 * (p), 0),     a01 = rdA(LAp, 2 * (p), 1);       \
        f16x8 a10 = rdA(LAp, 2 * (p) + 1, 0), a11 = rdA(LAp, 2 * (p) + 1, 1);   \
        STAGES;                                                                 \
        barrier_mf();                                                           \
        __builtin_amdgcn_s_setprio(1);                                          \
        _Pragma("unroll") for (int fb = 0; fb < 4; ++fb) {                      \
            acc[2*(p)][fb]   = __builtin_amdgcn_mfma_f32_16x16x32_f16(a00, bfr[fb][0], acc[2*(p)][fb],   0, 0, 0); \
            acc[2*(p)][fb]   = __builtin_amdgcn_mfma_f32_16x16x32_f16(a01, bfr[fb][1], acc[2*(p)][fb],   0, 0, 0); \
            acc[2*(p)+1][fb] = __builtin_amdgcn_mfma_f32_16x16x32_f16(a10, bfr[fb][0], acc[2*(p)+1][fb], 0, 0, 0); \
            acc[2*(p)+1][fb] = __builtin_amdgcn_mfma_f32_16x16x32_f16(a11, bfr[fb][1], acc[2*(p)+1][fb], 0, 0, 0); \
        }                                                                       \
        __builtin_amdgcn_s_setprio(0);                                          \
        barrier_mf();                                                           \
    }

    // Prologue: tile0 (A+B, 8 loads) then tile1.B (4 loads). FIFO order
    // matters: first top-guard vmcnt(4) completes exactly tile0.
    stage(Xf, m0, 0, A0, 0); stage(Xf, m0, 0, A0, 1);
    stage(Bg, n0, 0, B0, 0); stage(Bg, n0, 0, B0, 1);
    stage(Bg, n0, 1, B1, 0); stage(Bg, n0, 1, B1, 1);

    for (int it = 0; it < 8; ++it) {
        const int u = 2 * it;
        const bool nt = it < 7;
        // guard tile u (even -> buf0): u.A/u.B landed; (u+1).B may fly.
        asm volatile("s_waitcnt vmcnt(4)" ::: "memory");
        barrier_mf();
        PH(A0, B0, 0, { stage(Xf, m0, u + 1, A1, 0); }, true);
        PH(A0, B0, 1, { stage(Xf, m0, u + 1, A1, 1); }, false);
        PH(A0, B0, 2, { if (nt) stage(Bg, n0, u + 2, B0, 0); }, false);
        PH(A0, B0, 3, { if (nt) stage(Bg, n0, u + 2, B0, 1); }, false);
        // guard tile u+1 (buf1): (u+1).B [prev ph6,7] + (u+1).A [ph0,1] landed.
        if (nt) asm volatile("s_waitcnt vmcnt(4)" ::: "memory");
        else    asm volatile("s_waitcnt vmcnt(0)" ::: "memory");
        barrier_mf();
        PH(A1, B1, 0, { if (nt) stage(Xf, m0, u + 2, A0, 0); }, true);
        PH(A1, B1, 1, { if (nt) stage(Xf, m0, u + 2, A0, 1); }, false);
        PH(A1, B1, 2, { if (nt) stage(Bg, n0, u + 3, B1, 0); }, false);
        PH(A1, B1, 3, { if (nt) stage(Bg, n0, u + 3, B1, 1); }, false);
    }
#undef PH

    if (z == 1) {
        // V: store transposed Vt[b][d][s], fp16. 256-row tiles never straddle
        // a batch boundary (2048 % 256 == 0).
#pragma unroll
        for (int fr = 0; fr < 8; ++fr) {
            const int mg = m0 + wm * 128 + fr * 16 + q * 4;
            const int bb = mg >> 11, ss = mg & (SEQ - 1);
#pragma unroll
            for (int fb = 0; fb < 4; ++fb) {
                const int col = n0 + wn * 64 + fb * 16 + c;
                u16x4v v;
                v.x = f2h(acc[fr][fb][0]);
                v.y = f2h(acc[fr][fb][1]);
                v.z = f2h(acc[fr][fb][2]);
                v.w = f2h(acc[fr][fb][3]);
                *(u16x4v*)(Vt + ((size_t)bb * DIM + col) * SEQ + ss) = v;
            }
        }
    } else {
#pragma unroll
        for (int fr = 0; fr < 8; ++fr)
#pragma unroll
            for (int fb = 0; fb < 4; ++fb) {
                const int col = n0 + wn * 64 + fb * 16 + c;
#pragma unroll
                for (int r = 0; r < 4; ++r) {
                    const int row = m0 + wm * 128 + fr * 16 + q * 4 + r;
                    Yf[(size_t)row * DIM + col] = f2h(acc[fr][fb][r]);
                }
            }
    }
}

// ---------------------------------------------------------------------------
// Scores GEMM: S = Yf Xf^T * SCALE, fp16 out, scores==0 masked to 0xFC00 on
// the f32 accumulator. 1-D grid 544 = 8 XCD chunks x 68 consecutive
// triangular-t blocks (bijective): panel reuse stays within one L2.
// ---------------------------------------------------------------------------
__global__ __launch_bounds__(256) void scores_gemm1b(
    const unsigned short* __restrict__ Q, const unsigned short* __restrict__ K,
    unsigned short* __restrict__ S)
{
    __shared__ __attribute__((aligned(16))) unsigned short Ah[128 * 64];
    __shared__ __attribute__((aligned(16))) unsigned short Bh[128 * 64];
    const int flat = blockIdx.x;               // 0..543
    const int wg = (flat & 7) * 68 + (flat >> 3);  // XCD-chunked, bijective
    const int b = wg / 136;
    const int t = wg - b * 136;                // 0..135 triangular index
    int ti = (int)((__builtin_sqrtf(8.f * t + 1.f) - 1.f) * 0.5f);
    while ((ti + 1) * (ti + 2) / 2 <= t) ++ti;
    while (ti * (ti + 1) / 2 > t) --ti;
    const int tj = t - ti * (ti + 1) / 2;
    const int i0 = ti * 128, j0 = tj * 128;
    const unsigned short* Qb = Q + (size_t)b * SEQ * DIM;
    const unsigned short* Kb = K + (size_t)b * SEQ * DIM;
    unsigned short* Sb = S + (size_t)b * SEQ * SEQ;
    const int tid = threadIdx.x;
    const int w = tid >> 6, lane = tid & 63, q = lane >> 4, c = lane & 15;
    const int wrow = (w >> 1) * 64, wcol = (w & 1) * 64;
    const int g8 = lane >> 3;
    const int cu = (lane & 7) ^ g8;
    const int srow = w * 8 + g8;
    const int scol = cu * 8;
    unsigned short* lA = Ah + w * 512;
    unsigned short* lB = Bh + w * 512;
    const int c7 = c & 7;

    f32x4 acc[4][4];
#pragma unroll
    for (int a = 0; a < 4; ++a)
#pragma unroll
        for (int bq = 0; bq < 4; ++bq) acc[a][bq] = (f32x4){0.f, 0.f, 0.f, 0.f};

    for (int k0 = 0; k0 < DIM; k0 += 64) {
        __syncthreads();
        {
            const size_t ga = (size_t)(i0 + srow) * DIM + k0 + scol;
            const size_t gb = (size_t)(j0 + srow) * DIM + k0 + scol;
#pragma unroll
            for (int j = 0; j < 4; ++j) {
                gld_lds16(Qb + ga + (size_t)(j * 32) * DIM, lA + j * 2048);
                gld_lds16(Kb + gb + (size_t)(j * 32) * DIM, lB + j * 2048);
            }
        }
        __syncthreads();
#pragma unroll
        for (int kk = 0; kk < 2; ++kk) {
            f16x8 ah[4], bh[4];
#pragma unroll
            for (int mi = 0; mi < 4; ++mi)
                ah[mi] = ldsld(Ah + (wrow + mi * 16 + c) * 64 + (((kk << 2) + q) ^ c7) * 8);
#pragma unroll
            for (int ni = 0; ni < 4; ++ni)
                bh[ni] = ldsld(Bh + (wcol + ni * 16 + c) * 64 + (((kk << 2) + q) ^ c7) * 8);
#pragma unroll
            for (int mi = 0; mi < 4; ++mi)
#pragma unroll
                for (int ni = 0; ni < 4; ++ni)
                    acc[mi][ni] = __builtin_amdgcn_mfma_f32_16x16x32_f16(ah[mi], bh[ni], acc[mi][ni], 0, 0, 0);
        }
    }
#pragma unroll
    for (int mi = 0; mi < 4; ++mi)
#pragma unroll
        for (int ni = 0; ni < 4; ++ni) {
            const int col = j0 + wcol + ni * 16 + c;
#pragma unroll
            for (int r = 0; r < 4; ++r) {
                const int row = i0 + wrow + mi * 16 + q * 4 + r;
                const float sc = acc[mi][ni][r] * 0.03125f;
                Sb[(size_t)row * SEQ + col] =
                    (sc == 0.f) ? (unsigned short)0xFC00u : f2h(sc);
            }
        }
}

// ---------------------------------------------------------------------------
// Row-wise masked softmax: fp16 S -> fp16 P. j > i masked; scores==0 already
// -inf. Skip loads beyond i, skip writes beyond rowtile end. Grid (SEQ, BATCH).
// ---------------------------------------------------------------------------
__global__ __launch_bounds__(256) void softmax_row_b(
    const unsigned short* __restrict__ S, unsigned short* __restrict__ P)
{
    const int i = blockIdx.x, t = threadIdx.x;
    const size_t ro = ((size_t)blockIdx.y * SEQ + i) * SEQ;
    const int wid = t >> 6, lane = t & 63;
    __shared__ float redm[4], reds[4];
    const int j0 = t * 8;
    const int rti = (i & ~127) + 128;        // pv reads cols < rti only
    float sv[8];
    float mx = -__builtin_inff();
    if (j0 <= i) {
        u16x8v raw = *(const u16x8v*)(S + ro + j0);
#pragma unroll
        for (int u = 0; u < 8; ++u) {
            float s = (j0 + u <= i) ? h2f(raw[u]) : -__builtin_inff();
            sv[u] = s;
            mx = fmaxf(mx, s);
        }
    } else {
#pragma unroll
        for (int u = 0; u < 8; ++u) sv[u] = -__builtin_inff();
    }
#pragma unroll
    for (int off = 1; off < 64; off <<= 1) mx = fmaxf(mx, __shfl_xor(mx, off));
    if (lane == 0) redm[wid] = mx;
    __syncthreads();
    const float M = fmaxf(fmaxf(redm[0], redm[1]), fmaxf(redm[2], redm[3]));
    float sum = 0.f;
#pragma unroll
    for (int u = 0; u < 8; ++u) {
        float e = __expf(sv[u] - M);
        sv[u] = e;
        sum += e;
    }
#pragma unroll
    for (int off = 1; off < 64; off <<= 1) sum += __shfl_xor(sum, off);
    if (lane == 0) reds[wid] = sum;
    __syncthreads();
    const float rinv = 1.f / (reds[0] + reds[1] + reds[2] + reds[3]);
    if (j0 < rti) {
        u16x8v o;
#pragma unroll
        for (int u = 0; u < 8; ++u) o[u] = f2h(sv[u] * rinv);
        *(u16x8v*)(P + ro + j0) = o;
    }
}

// ---------------------------------------------------------------------------
// out = P @ V via Vt (NT MFMA, fp16), fp32 store. 128x128 tile, BK=64
// swizzled; k-loop truncated at causal bound. 512 blocks (2/CU), XCD-chunked
// 1-D grid: XCD x owns 4 complete (b,d0) groups x 16 i0t tiles (512 KB Vt
// panel + batch P stay L2-resident; equal work per XCD).
// ---------------------------------------------------------------------------
__global__ __launch_bounds__(256) void pv_gemm(
    const unsigned short* __restrict__ Pm, const unsigned short* __restrict__ Vt,
    float* __restrict__ Out)
{
    __shared__ __attribute__((aligned(16))) unsigned short Ps[128 * 64];
    __shared__ __attribute__((aligned(16))) unsigned short Vs[128 * 64];
    const int flat = blockIdx.x;             // 0..511
    const int wg = (flat & 7) * 64 + (flat >> 3);  // XCD-chunked, bijective
    const int i0t = wg & 15;
    const int grp = wg >> 4;                 // 0..31
    const int b = grp >> 3;
    const int d0 = (grp & 7) * 128;
    const int i0 = i0t * 128;
    const int tid = threadIdx.x;
    const int w = tid >> 6, lane = tid & 63, q = lane >> 4, c = lane & 15;
    const int wrow = (w >> 1) * 64, wcol = (w & 1) * 64;
    const int g8 = lane >> 3;
    const int cu = (lane & 7) ^ g8;
    const int srow = w * 8 + g8;
    const int scol = cu * 8;
    unsigned short* lA = Ps + w * 512;
    unsigned short* lB = Vs + w * 512;
    const int c7 = c & 7;

    f32x4 acc[4][4];
#pragma unroll
    for (int a = 0; a < 4; ++a)
#pragma unroll
        for (int bq = 0; bq < 4; ++bq) acc[a][bq] = (f32x4){0.f, 0.f, 0.f, 0.f};

    const int njs = 2 * i0t + 2;  // covers cols < i0+128

    for (int ks = 0; ks < njs; ++ks) {
        const int j0 = ks * 64;
        __syncthreads();
        {
            const size_t gpa = ((size_t)b * SEQ + i0 + srow) * SEQ + j0 + scol;
            const size_t gva = ((size_t)b * DIM + d0 + srow) * SEQ + j0 + scol;
#pragma unroll
            for (int j = 0; j < 4; ++j) {
                gld_lds16(Pm + gpa + (size_t)(j * 32) * SEQ, lA + j * 2048);
                gld_lds16(Vt + gva + (size_t)(j * 32) * SEQ, lB + j * 2048);
            }
        }
        __syncthreads();
#pragma unroll
        for (int kk = 0; kk < 2; ++kk) {
            f16x8 ah[4], bh[4];
#pragma unroll
            for (int mi = 0; mi < 4; ++mi)
                ah[mi] = ldsld(Ps + (wrow + mi * 16 + c) * 64 + (((kk << 2) + q) ^ c7) * 8);
#pragma unroll
            for (int ni = 0; ni < 4; ++ni)
                bh[ni] = ldsld(Vs + (wcol + ni * 16 + c) * 64 + (((kk << 2) + q) ^ c7) * 8);
#pragma unroll
            for (int mi = 0; mi < 4; ++mi)
#pragma unroll
                for (int ni = 0; ni < 4; ++ni)
                    acc[mi][ni] = __builtin_amdgcn_mfma_f32_16x16x32_f16(ah[mi], bh[ni], acc[mi][ni], 0, 0, 0);
        }
    }
#pragma unroll
    for (int mi = 0; mi < 4; ++mi)
#pragma unroll
        for (int ni = 0; ni < 4; ++ni) {
            const int dcol = d0 + wcol + ni * 16 + c;
#pragma unroll
            for (int r = 0; r < 4; ++r) {
                const int i = i0 + wrow + mi * 16 + q * 4 + r;
                Out[((size_t)b * SEQ + i) * DIM + dcol] = acc[mi][ni][r];
            }
        }
}

extern "C" void kernel_launch(void* const* d_in, const int* in_sizes, int n_in,
                              void* d_out, int out_size, void* d_ws, size_t ws_size,
                              hipStream_t stream)
{
    (void)out_size; (void)ws_size;
    const float* X = nullptr;
    const float* Wv[3] = {nullptr, nullptr, nullptr};
    int nw = 0;
    for (int i = 0; i < n_in; ++i) {
        if (in_sizes[i] == (int)NBS)
            X = (const float*)d_in[i];
        else if (nw < 3)
            Wv[nw++] = (const float*)d_in[i];
    }

    unsigned short* ws = (unsigned short*)d_ws;
    unsigned short* Yf = ws;                 // 16 MB
    unsigned short* Vt = ws + 2 * NBS;       // 16 MB
    unsigned short* Xf = ws + 3 * NBS;       // consumed by yv + scores
    unsigned short* Pp = ws + 3 * NBS;       // P aliases Xf after scores (32 MB)
    unsigned short* Sb = ws + 5 * NBS;       // fp16 S, all batches (32 MB)
    unsigned short* Wf = ws + 7 * NBS;       // 6 MB (Wq,Wk,Wv fp16)
    unsigned short* Mtb = Wf + (size_t)3 * DIM * DIM;   // 2 MB
    unsigned short* WqT = Mtb + (size_t)DIM * DIM;      // 2 MB
    unsigned short* WkT = WqT + (size_t)DIM * DIM;      // 2 MB
    float* Out = (float*)d_out;

    // Wv[0]=WQ, Wv[1]=WK, Wv[2]=WV (input order).
    cvt_all<<<dim3(8192 + 3072 + 512), 256, 0, stream>>>(
        X, Wv[0], Wv[1], Wv[2], Xf, Wf, WqT, WkT);

    mt_gemm<<<dim3(8, 8), 256, 0, stream>>>(WkT, WqT, Mtb);

    yv8_gemm<<<dim3(32, 4, 2), 512, 0, stream>>>(
        Xf, Mtb, Wf + (size_t)2 * DIM * DIM, Yf, Vt);

    scores_gemm1b<<<dim3(544), 256, 0, stream>>>(Yf, Xf, Sb);
    softmax_row_b<<<dim3(SEQ, BATCH), 256, 0, stream>>>(Sb, Pp);

    pv_gemm<<<dim3(512), 256, 0, stream>>>(Pp, Vt, Out);
}

// Round 12
// 231.007 us; speedup vs baseline: 1.0656x; 1.0200x over previous
//
#include <hip/hip_runtime.h>

typedef _Float16 f16x8 __attribute__((ext_vector_type(8)));
typedef unsigned short u16x8v __attribute__((ext_vector_type(8)));
typedef unsigned short u16x4v __attribute__((ext_vector_type(4)));
typedef float f32x4 __attribute__((ext_vector_type(4)));

constexpr int SEQ = 2048;
constexpr int DIM = 1024;
constexpr int BATCH = 4;
constexpr size_t NBS = (size_t)BATCH * SEQ * DIM;  // 8388608

static __device__ __forceinline__ unsigned short f2h(float f) {
    return __builtin_bit_cast(unsigned short, (_Float16)f);  // RNE
}
static __device__ __forceinline__ float h2f(unsigned short u) {
    return (float)__builtin_bit_cast(_Float16, u);
}
static __device__ __forceinline__ f16x8 ldsld(const unsigned short* p) {
    return __builtin_bit_cast(f16x8, *(const u16x8v*)p);
}
// Async global->LDS, 16B/lane. LDS dest = wave-uniform base + lane*16B.
static __device__ __forceinline__ void gld_lds16(const unsigned short* g, unsigned short* l) {
    __builtin_amdgcn_global_load_lds(
        (const __attribute__((address_space(1))) void*)g,
        (__attribute__((address_space(3))) void*)l, 16, 0, 0);
}
// Barrier that is also a compiler memory fence.
static __device__ __forceinline__ void barrier_mf() {
    asm volatile("s_barrier" ::: "memory");
}

// ---------------------------------------------------------------------------
// cvt + transpose, ONE launch. Transpose blocks FIRST (r12): their strided
// fp32 reads have the longest per-block latency; dispatching them at b<512
// hides that latency under the 11264 streaming cvt blocks instead of
// extending the kernel tail.
//   [0,512):             WqT/WkT fp32 -> fp16 TRANSPOSED [e][k].
//   [512,512+8192):      X fp32 -> fp16.
//   [8704,8704+3072):    Wq,Wk,Wv fp32 -> fp16 (k-major, as input).
// ---------------------------------------------------------------------------
__global__ __launch_bounds__(256) void cvt_all(
    const float* __restrict__ X,
    const float* __restrict__ W0, const float* __restrict__ W1,
    const float* __restrict__ W2,
    unsigned short* __restrict__ Xf, unsigned short* __restrict__ Wf,
    unsigned short* __restrict__ WqT, unsigned short* __restrict__ WkT)
{
    __shared__ __attribute__((aligned(16))) unsigned short T[64][72];
    const int b = blockIdx.x;
    const int t = threadIdx.x;
    if (b >= 512) {
        const int cb = b - 512;
        const float* src;
        unsigned short* dst;
        int i;
        if (cb < 8192) {
            src = X; dst = Xf;
            i = cb * 256 + t;
        } else {
            const int wb = cb - 8192;
            const int z = wb >> 10;
            src = (z == 0) ? W0 : (z == 1) ? W1 : W2;
            dst = Wf + (size_t)z * DIM * DIM;
            i = (wb & 1023) * 256 + t;
        }
        float4 f = ((const float4*)src)[i];
        u16x4v h;
        h.x = f2h(f.x); h.y = f2h(f.y); h.z = f2h(f.z); h.w = f2h(f.w);
        ((u16x4v*)dst)[i] = h;
        return;
    }
    const int tb = b;                            // 0..511
    const float* src = (tb < 256) ? W0 : W1;     // Wq then Wk
    unsigned short* dst = (tb < 256) ? WqT : WkT;
    const int tile = tb & 255;
    const int tk = (tile >> 4) * 64;
    const int te = (tile & 15) * 64;
    const int cu = t & 15, kr4 = t >> 4;
#pragma unroll
    for (int p = 0; p < 4; ++p) {
        const int k = p * 16 + kr4;
        float4 v = *(const float4*)(src + (size_t)(tk + k) * DIM + te + cu * 4);
        T[cu * 4 + 0][k] = f2h(v.x);
        T[cu * 4 + 1][k] = f2h(v.y);
        T[cu * 4 + 2][k] = f2h(v.z);
        T[cu * 4 + 3][k] = f2h(v.w);
    }
    __syncthreads();
    const int un = t & 7, er = t >> 3;
#pragma unroll
    for (int p = 0; p < 2; ++p) {
        const int e = p * 32 + er;
        *(u16x8v*)(dst + (size_t)(te + e) * DIM + tk + un * 8) =
            *(const u16x8v*)&T[e][un * 8];
    }
}

// ---------------------------------------------------------------------------
// Mt[e'][e] = sum_k Wk[k][e'] Wq[k][e], NT GEMM on transposed copies.
// ---------------------------------------------------------------------------
__global__ __launch_bounds__(256) void mt_gemm(
    const unsigned short* __restrict__ WkTp, const unsigned short* __restrict__ WqTp,
    unsigned short* __restrict__ Mt)
{
    __shared__ __attribute__((aligned(16))) unsigned short Ah[128 * 64];
    __shared__ __attribute__((aligned(16))) unsigned short Bh[128 * 64];
    const int m0 = blockIdx.x * 128, n0 = blockIdx.y * 128;
    const int tid = threadIdx.x;
    const int w = tid >> 6, lane = tid & 63, q = lane >> 4, c = lane & 15;
    const int wrow = (w >> 1) * 64, wcol = (w & 1) * 64;
    const int g8 = lane >> 3;
    const int cu = (lane & 7) ^ g8;
    const int srow = w * 8 + g8;
    const int scol = cu * 8;
    unsigned short* lA = Ah + w * 512;
    unsigned short* lB = Bh + w * 512;
    const int c7 = c & 7;

    f32x4 acc[4][4];
#pragma unroll
    for (int a = 0; a < 4; ++a)
#pragma unroll
        for (int bq = 0; bq < 4; ++bq) acc[a][bq] = (f32x4){0.f, 0.f, 0.f, 0.f};

    for (int k0 = 0; k0 < DIM; k0 += 64) {
        __syncthreads();
        {
            const size_t ga = (size_t)(m0 + srow) * DIM + k0 + scol;
            const size_t gb = (size_t)(n0 + srow) * DIM + k0 + scol;
#pragma unroll
            for (int j = 0; j < 4; ++j) {
                gld_lds16(WkTp + ga + (size_t)(j * 32) * DIM, lA + j * 2048);
                gld_lds16(WqTp + gb + (size_t)(j * 32) * DIM, lB + j * 2048);
            }
        }
        __syncthreads();
#pragma unroll
        for (int kk = 0; kk < 2; ++kk) {
            f16x8 af[4], bf[4];
#pragma unroll
            for (int mi = 0; mi < 4; ++mi)
                af[mi] = ldsld(Ah + (wrow + mi * 16 + c) * 64 + (((kk << 2) + q) ^ c7) * 8);
#pragma unroll
            for (int ni = 0; ni < 4; ++ni)
                bf[ni] = ldsld(Bh + (wcol + ni * 16 + c) * 64 + (((kk << 2) + q) ^ c7) * 8);
#pragma unroll
            for (int mi = 0; mi < 4; ++mi)
#pragma unroll
                for (int ni = 0; ni < 4; ++ni)
                    acc[mi][ni] = __builtin_amdgcn_mfma_f32_16x16x32_f16(af[mi], bf[ni], acc[mi][ni], 0, 0, 0);
        }
    }
#pragma unroll
    for (int mi = 0; mi < 4; ++mi)
#pragma unroll
        for (int ni = 0; ni < 4; ++ni) {
            const int col = n0 + wcol + ni * 16 + c;
#pragma unroll
            for (int r = 0; r < 4; ++r) {
                const int row = m0 + wrow + mi * 16 + q * 4 + r;
                Mt[(size_t)row * DIM + col] = f2h(acc[mi][ni][r]);
            }
        }
}

// ---------------------------------------------------------------------------
// Y/V projection, 256x256 tile, 8-phase counted-vmcnt schedule (r11,
// refcheck'd). z=0: Y = NT(Xf, Mt); z=1: V = NT(Xf, Wvf) -> Vt[b][d][s].
// ---------------------------------------------------------------------------
__global__ __launch_bounds__(512) void yv8_gemm(
    const unsigned short* __restrict__ Xf, const unsigned short* __restrict__ Mt,
    const unsigned short* __restrict__ Wvf,
    unsigned short* __restrict__ Yf, unsigned short* __restrict__ Vt)
{
    __shared__ __attribute__((aligned(16))) unsigned short L[65536];  // 128 KB
    unsigned short* A0 = L;
    unsigned short* B0 = L + 16384;
    unsigned short* A1 = L + 32768;
    unsigned short* B1 = L + 49152;

    const int m0 = blockIdx.x * 256, n0 = blockIdx.y * 256, z = blockIdx.z;
    const unsigned short* Bg = z ? Wvf : Mt;
    const int tid = threadIdx.x;
    const int w = tid >> 6, lane = tid & 63;
    const int wm = w >> 2, wn = w & 3;          // 2M x 4N waves
    const int c = lane & 15, q = lane >> 4, c7 = c & 7;
    const int sl8 = lane >> 3;                  // staging row-in-8
    const int gu = ((lane & 7) ^ sl8) * 8;      // inverse-swizzled col (shorts)

    auto stage = [&](const unsigned short* G, int roff, int T, unsigned short* Lb, int h) {
        const int rb0 = h * 128 + w * 16;
        const int kb = T * 64 + gu;
        gld_lds16(G + (size_t)(roff + rb0 + sl8) * DIM + kb, Lb + rb0 * 64 + lane * 8);
        gld_lds16(G + (size_t)(roff + rb0 + 8 + sl8) * DIM + kb, Lb + (rb0 + 8) * 64 + lane * 8);
    };
    auto rdA = [&](const unsigned short* LA, int fr, int kk) {
        const int row = wm * 128 + fr * 16 + c;
        return ldsld(LA + row * 64 + (((kk << 2) + q) ^ c7) * 8);
    };
    auto rdB = [&](const unsigned short* LB, int fb, int kk) {
        const int row = wn * 64 + fb * 16 + c;
        return ldsld(LB + row * 64 + (((kk << 2) + q) ^ c7) * 8);
    };

    f32x4 acc[8][4];
#pragma unroll
    for (int a = 0; a < 8; ++a)
#pragma unroll
        for (int bq = 0; bq < 4; ++bq) acc[a][bq] = (f32x4){0.f, 0.f, 0.f, 0.f};
    f16x8 bfr[4][2];

#define PH(LAp, LBp, p, STAGES, LOADB)                                          \
    {                                                                           \
        if (LOADB) {                                                            \
            _Pragma("unroll") for (int fb = 0; fb < 4; ++fb) {                  \
                bfr[fb][0] = rdB(LBp, fb, 0);                                   \
                bfr[fb][1] = rdB(LBp, fb, 1);                                   \
            }                                                                   \
        }                                                                       \
        f16x8 a00 = rdA(LAp, 2 * (p), 0),     a01 = rdA(LAp, 2 * (p), 1);       \
        f16x8 a10 = rdA(LAp, 2 * (p) + 1, 0), a11 = rdA(LAp, 2 * (p) + 1, 1);   \
        STAGES;                                                                 \
        barrier_mf();                                                           \
        __builtin_amdgcn_s_setprio(1);                                          \
        _Pragma("unroll") for (int fb = 0; fb < 4; ++fb) {                      \
            acc[2*(p)][fb]   = __builtin_amdgcn_mfma_f32_16x16x32_f16(a00, bfr[fb][0], acc[2*(p)][fb],   0, 0, 0); \
            acc[2*(p)][fb]   = __builtin_amdgcn_mfma_f32_16x16x32_f16(a01, bfr[fb][1], acc[2*(p)][fb],   0, 0, 0); \
            acc[2*(p)+1][fb] = __builtin_amdgcn_mfma_f32_16x16x32_f16(a10, bfr[fb][0], acc[2*(p)+1][fb], 0, 0, 0); \
            acc[2*(p)+1][fb] = __builtin_amdgcn_mfma_f32_16x16x32_f16(a11, bfr[fb][1], acc[2*(p)+1][fb], 0, 0, 0); \
        }                                                                       \
        __builtin_amdgcn_s_setprio(0);                                          \
        barrier_mf();                                                           \
    }

    stage(Xf, m0, 0, A0, 0); stage(Xf, m0, 0, A0, 1);
    stage(Bg, n0, 0, B0, 0); stage(Bg, n0, 0, B0, 1);
    stage(Bg, n0, 1, B1, 0); stage(Bg, n0, 1, B1, 1);

    for (int it = 0; it < 8; ++it) {
        const int u = 2 * it;
        const bool nt = it < 7;
        asm volatile("s_waitcnt vmcnt(4)" ::: "memory");
        barrier_mf();
        PH(A0, B0, 0, { stage(Xf, m0, u + 1, A1, 0); }, true);
        PH(A0, B0, 1, { stage(Xf, m0, u + 1, A1, 1); }, false);
        PH(A0, B0, 2, { if (nt) stage(Bg, n0, u + 2, B0, 0); }, false);
        PH(A0, B0, 3, { if (nt) stage(Bg, n0, u + 2, B0, 1); }, false);
        if (nt) asm volatile("s_waitcnt vmcnt(4)" ::: "memory");
        else    asm volatile("s_waitcnt vmcnt(0)" ::: "memory");
        barrier_mf();
        PH(A1, B1, 0, { if (nt) stage(Xf, m0, u + 2, A0, 0); }, true);
        PH(A1, B1, 1, { if (nt) stage(Xf, m0, u + 2, A0, 1); }, false);
        PH(A1, B1, 2, { if (nt) stage(Bg, n0, u + 3, B1, 0); }, false);
        PH(A1, B1, 3, { if (nt) stage(Bg, n0, u + 3, B1, 1); }, false);
    }
#undef PH

    if (z == 1) {
#pragma unroll
        for (int fr = 0; fr < 8; ++fr) {
            const int mg = m0 + wm * 128 + fr * 16 + q * 4;
            const int bb = mg >> 11, ss = mg & (SEQ - 1);
#pragma unroll
            for (int fb = 0; fb < 4; ++fb) {
                const int col = n0 + wn * 64 + fb * 16 + c;
                u16x4v v;
                v.x = f2h(acc[fr][fb][0]);
                v.y = f2h(acc[fr][fb][1]);
                v.z = f2h(acc[fr][fb][2]);
                v.w = f2h(acc[fr][fb][3]);
                *(u16x4v*)(Vt + ((size_t)bb * DIM + col) * SEQ + ss) = v;
            }
        }
    } else {
#pragma unroll
        for (int fr = 0; fr < 8; ++fr)
#pragma unroll
            for (int fb = 0; fb < 4; ++fb) {
                const int col = n0 + wn * 64 + fb * 16 + c;
#pragma unroll
                for (int r = 0; r < 4; ++r) {
                    const int row = m0 + wm * 128 + fr * 16 + q * 4 + r;
                    Yf[(size_t)row * DIM + col] = f2h(acc[fr][fb][r]);
                }
            }
    }
}

// ---------------------------------------------------------------------------
// Scores GEMM: S = Yf Xf^T * SCALE, fp16 out, scores==0 masked to 0xFC00 on
// the f32 accumulator. 1-D grid 544 = 8 XCD chunks x 68 consecutive
// triangular-t blocks (bijective): panel reuse stays within one L2.
// ---------------------------------------------------------------------------
__global__ __launch_bounds__(256) void scores_gemm1b(
    const unsigned short* __restrict__ Q, const unsigned short* __restrict__ K,
    unsigned short* __restrict__ S)
{
    __shared__ __attribute__((aligned(16))) unsigned short Ah[128 * 64];
    __shared__ __attribute__((aligned(16))) unsigned short Bh[128 * 64];
    const int flat = blockIdx.x;               // 0..543
    const int wg = (flat & 7) * 68 + (flat >> 3);  // XCD-chunked, bijective
    const int b = wg / 136;
    const int t = wg - b * 136;                // 0..135 triangular index
    int ti = (int)((__builtin_sqrtf(8.f * t + 1.f) - 1.f) * 0.5f);
    while ((ti + 1) * (ti + 2) / 2 <= t) ++ti;
    while (ti * (ti + 1) / 2 > t) --ti;
    const int tj = t - ti * (ti + 1) / 2;
    const int i0 = ti * 128, j0 = tj * 128;
    const unsigned short* Qb = Q + (size_t)b * SEQ * DIM;
    const unsigned short* Kb = K + (size_t)b * SEQ * DIM;
    unsigned short* Sb = S + (size_t)b * SEQ * SEQ;
    const int tid = threadIdx.x;
    const int w = tid >> 6, lane = tid & 63, q = lane >> 4, c = lane & 15;
    const int wrow = (w >> 1) * 64, wcol = (w & 1) * 64;
    const int g8 = lane >> 3;
    const int cu = (lane & 7) ^ g8;
    const int srow = w * 8 + g8;
    const int scol = cu * 8;
    unsigned short* lA = Ah + w * 512;
    unsigned short* lB = Bh + w * 512;
    const int c7 = c & 7;

    f32x4 acc[4][4];
#pragma unroll
    for (int a = 0; a < 4; ++a)
#pragma unroll
        for (int bq = 0; bq < 4; ++bq) acc[a][bq] = (f32x4){0.f, 0.f, 0.f, 0.f};

    for (int k0 = 0; k0 < DIM; k0 += 64) {
        __syncthreads();
        {
            const size_t ga = (size_t)(i0 + srow) * DIM + k0 + scol;
            const size_t gb = (size_t)(j0 + srow) * DIM + k0 + scol;
#pragma unroll
            for (int j = 0; j < 4; ++j) {
                gld_lds16(Qb + ga + (size_t)(j * 32) * DIM, lA + j * 2048);
                gld_lds16(Kb + gb + (size_t)(j * 32) * DIM, lB + j * 2048);
            }
        }
        __syncthreads();
#pragma unroll
        for (int kk = 0; kk < 2; ++kk) {
            f16x8 ah[4], bh[4];
#pragma unroll
            for (int mi = 0; mi < 4; ++mi)
                ah[mi] = ldsld(Ah + (wrow + mi * 16 + c) * 64 + (((kk << 2) + q) ^ c7) * 8);
#pragma unroll
            for (int ni = 0; ni < 4; ++ni)
                bh[ni] = ldsld(Bh + (wcol + ni * 16 + c) * 64 + (((kk << 2) + q) ^ c7) * 8);
#pragma unroll
            for (int mi = 0; mi < 4; ++mi)
#pragma unroll
                for (int ni = 0; ni < 4; ++ni)
                    acc[mi][ni] = __builtin_amdgcn_mfma_f32_16x16x32_f16(ah[mi], bh[ni], acc[mi][ni], 0, 0, 0);
        }
    }
#pragma unroll
    for (int mi = 0; mi < 4; ++mi)
#pragma unroll
        for (int ni = 0; ni < 4; ++ni) {
            const int col = j0 + wcol + ni * 16 + c;
#pragma unroll
            for (int r = 0; r < 4; ++r) {
                const int row = i0 + wrow + mi * 16 + q * 4 + r;
                const float sc = acc[mi][ni][r] * 0.03125f;
                Sb[(size_t)row * SEQ + col] =
                    (sc == 0.f) ? (unsigned short)0xFC00u : f2h(sc);
            }
        }
}

// ---------------------------------------------------------------------------
// Row-wise masked softmax: fp16 S -> fp16 P. j > i masked; scores==0 already
// -inf. Skip loads beyond i, skip writes beyond rowtile end. Grid (SEQ, BATCH).
// ---------------------------------------------------------------------------
__global__ __launch_bounds__(256) void softmax_row_b(
    const unsigned short* __restrict__ S, unsigned short* __restrict__ P)
{
    const int i = blockIdx.x, t = threadIdx.x;
    const size_t ro = ((size_t)blockIdx.y * SEQ + i) * SEQ;
    const int wid = t >> 6, lane = t & 63;
    __shared__ float redm[4], reds[4];
    const int j0 = t * 8;
    const int rti = (i & ~127) + 128;        // pv reads cols < rti only
    float sv[8];
    float mx = -__builtin_inff();
    if (j0 <= i) {
        u16x8v raw = *(const u16x8v*)(S + ro + j0);
#pragma unroll
        for (int u = 0; u < 8; ++u) {
            float s = (j0 + u <= i) ? h2f(raw[u]) : -__builtin_inff();
            sv[u] = s;
            mx = fmaxf(mx, s);
        }
    } else {
#pragma unroll
        for (int u = 0; u < 8; ++u) sv[u] = -__builtin_inff();
    }
#pragma unroll
    for (int off = 1; off < 64; off <<= 1) mx = fmaxf(mx, __shfl_xor(mx, off));
    if (lane == 0) redm[wid] = mx;
    __syncthreads();
    const float M = fmaxf(fmaxf(redm[0], redm[1]), fmaxf(redm[2], redm[3]));
    float sum = 0.f;
#pragma unroll
    for (int u = 0; u < 8; ++u) {
        float e = __expf(sv[u] - M);
        sv[u] = e;
        sum += e;
    }
#pragma unroll
    for (int off = 1; off < 64; off <<= 1) sum += __shfl_xor(sum, off);
    if (lane == 0) reds[wid] = sum;
    __syncthreads();
    const float rinv = 1.f / (reds[0] + reds[1] + reds[2] + reds[3]);
    if (j0 < rti) {
        u16x8v o;
#pragma unroll
        for (int u = 0; u < 8; ++u) o[u] = f2h(sv[u] * rinv);
        *(u16x8v*)(P + ro + j0) = o;
    }
}

// ---------------------------------------------------------------------------
// out = P @ V via Vt (NT MFMA, fp16), fp32 store. 128x128 tile, BK=64
// swizzled; k-loop truncated at causal bound. 512 blocks (2/CU), XCD-chunked
// 1-D grid: XCD x owns 4 complete (b,d0) groups x 16 i0t tiles (512 KB Vt
// panel + batch P stay L2-resident; equal work per XCD).
// ---------------------------------------------------------------------------
__global__ __launch_bounds__(256) void pv_gemm(
    const unsigned short* __restrict__ Pm, const unsigned short* __restrict__ Vt,
    float* __restrict__ Out)
{
    __shared__ __attribute__((aligned(16))) unsigned short Ps[128 * 64];
    __shared__ __attribute__((aligned(16))) unsigned short Vs[128 * 64];
    const int flat = blockIdx.x;             // 0..511
    const int wg = (flat & 7) * 64 + (flat >> 3);  // XCD-chunked, bijective
    const int i0t = wg & 15;
    const int grp = wg >> 4;                 // 0..31
    const int b = grp >> 3;
    const int d0 = (grp & 7) * 128;
    const int i0 = i0t * 128;
    const int tid = threadIdx.x;
    const int w = tid >> 6, lane = tid & 63, q = lane >> 4, c = lane & 15;
    const int wrow = (w >> 1) * 64, wcol = (w & 1) * 64;
    const int g8 = lane >> 3;
    const int cu = (lane & 7) ^ g8;
    const int srow = w * 8 + g8;
    const int scol = cu * 8;
    unsigned short* lA = Ps + w * 512;
    unsigned short* lB = Vs + w * 512;
    const int c7 = c & 7;

    f32x4 acc[4][4];
#pragma unroll
    for (int a = 0; a < 4; ++a)
#pragma unroll
        for (int bq = 0; bq < 4; ++bq) acc[a][bq] = (f32x4){0.f, 0.f, 0.f, 0.f};

    const int njs = 2 * i0t + 2;  // covers cols < i0+128

    for (int ks = 0; ks < njs; ++ks) {
        const int j0 = ks * 64;
        __syncthreads();
        {
            const size_t gpa = ((size_t)b * SEQ + i0 + srow) * SEQ + j0 + scol;
            const size_t gva = ((size_t)b * DIM + d0 + srow) * SEQ + j0 + scol;
#pragma unroll
            for (int j = 0; j < 4; ++j) {
                gld_lds16(Pm + gpa + (size_t)(j * 32) * SEQ, lA + j * 2048);
                gld_lds16(Vt + gva + (size_t)(j * 32) * SEQ, lB + j * 2048);
            }
        }
        __syncthreads();
#pragma unroll
        for (int kk = 0; kk < 2; ++kk) {
            f16x8 ah[4], bh[4];
#pragma unroll
            for (int mi = 0; mi < 4; ++mi)
                ah[mi] = ldsld(Ps + (wrow + mi * 16 + c) * 64 + (((kk << 2) + q) ^ c7) * 8);
#pragma unroll
            for (int ni = 0; ni < 4; ++ni)
                bh[ni] = ldsld(Vs + (wcol + ni * 16 + c) * 64 + (((kk << 2) + q) ^ c7) * 8);
#pragma unroll
            for (int mi = 0; mi < 4; ++mi)
#pragma unroll
                for (int ni = 0; ni < 4; ++ni)
                    acc[mi][ni] = __builtin_amdgcn_mfma_f32_16x16x32_f16(ah[mi], bh[ni], acc[mi][ni], 0, 0, 0);
        }
    }
#pragma unroll
    for (int mi = 0; mi < 4; ++mi)
#pragma unroll
        for (int ni = 0; ni < 4; ++ni) {
            const int dcol = d0 + wcol + ni * 16 + c;
#pragma unroll
            for (int r = 0; r < 4; ++r) {
                const int i = i0 + wrow + mi * 16 + q * 4 + r;
                Out[((size_t)b * SEQ + i) * DIM + dcol] = acc[mi][ni][r];
            }
        }
}

extern "C" void kernel_launch(void* const* d_in, const int* in_sizes, int n_in,
                              void* d_out, int out_size, void* d_ws, size_t ws_size,
                              hipStream_t stream)
{
    (void)out_size; (void)ws_size;
    const float* X = nullptr;
    const float* Wv[3] = {nullptr, nullptr, nullptr};
    int nw = 0;
    for (int i = 0; i < n_in; ++i) {
        if (in_sizes[i] == (int)NBS)
            X = (const float*)d_in[i];
        else if (nw < 3)
            Wv[nw++] = (const float*)d_in[i];
    }

    unsigned short* ws = (unsigned short*)d_ws;
    unsigned short* Yf = ws;                 // 16 MB
    unsigned short* Vt = ws + 2 * NBS;       // 16 MB
    unsigned short* Xf = ws + 3 * NBS;       // consumed by yv + scores
    unsigned short* Pp = ws + 3 * NBS;       // P aliases Xf after scores (32 MB)
    unsigned short* Sb = ws + 5 * NBS;       // fp16 S, all batches (32 MB)
    unsigned short* Wf = ws + 7 * NBS;       // 6 MB (Wq,Wk,Wv fp16)
    unsigned short* Mtb = Wf + (size_t)3 * DIM * DIM;   // 2 MB
    unsigned short* WqT = Mtb + (size_t)DIM * DIM;      // 2 MB
    unsigned short* WkT = WqT + (size_t)DIM * DIM;      // 2 MB
    float* Out = (float*)d_out;

    // Wv[0]=WQ, Wv[1]=WK, Wv[2]=WV (input order).
    cvt_all<<<dim3(512 + 8192 + 3072), 256, 0, stream>>>(
        X, Wv[0], Wv[1], Wv[2], Xf, Wf, WqT, WkT);

    mt_gemm<<<dim3(8, 8), 256, 0, stream>>>(WkT, WqT, Mtb);

    yv8_gemm<<<dim3(32, 4, 2), 512, 0, stream>>>(
        Xf, Mtb, Wf + (size_t)2 * DIM * DIM, Yf, Vt);

    scores_gemm1b<<<dim3(544), 256, 0, stream>>>(Yf, Xf, Sb);
    softmax_row_b<<<dim3(SEQ, BATCH), 256, 0, stream>>>(Sb, Pp);

    pv_gemm<<<dim3(512), 256, 0, stream>>>(Pp, Vt, Out);
}

// Round 13
// 230.622 us; speedup vs baseline: 1.0673x; 1.0017x over previous
//
#include <hip/hip_runtime.h>

typedef _Float16 f16x8 __attribute__((ext_vector_type(8)));
typedef unsigned short u16x8v __attribute__((ext_vector_type(8)));
typedef unsigned short u16x4v __attribute__((ext_vector_type(4)));
typedef float f32x4 __attribute__((ext_vector_type(4)));

constexpr int SEQ = 2048;
constexpr int DIM = 1024;
constexpr int BATCH = 4;
constexpr size_t NBS = (size_t)BATCH * SEQ * DIM;  // 8388608

static __device__ __forceinline__ unsigned short f2h(float f) {
    return __builtin_bit_cast(unsigned short, (_Float16)f);  // RNE
}
static __device__ __forceinline__ float h2f(unsigned short u) {
    return (float)__builtin_bit_cast(_Float16, u);
}
static __device__ __forceinline__ f16x8 ldsld(const unsigned short* p) {
    return __builtin_bit_cast(f16x8, *(const u16x8v*)p);
}
// Async global->LDS, 16B/lane. LDS dest = wave-uniform base + lane*16B.
static __device__ __forceinline__ void gld_lds16(const unsigned short* g, unsigned short* l) {
    __builtin_amdgcn_global_load_lds(
        (const __attribute__((address_space(1))) void*)g,
        (__attribute__((address_space(3))) void*)l, 16, 0, 0);
}
// Barrier that is also a compiler memory fence.
static __device__ __forceinline__ void barrier_mf() {
    asm volatile("s_barrier" ::: "memory");
}

// ---------------------------------------------------------------------------
// cvt + transpose, ONE launch. Transpose blocks FIRST: their strided fp32
// reads have the longest per-block latency; dispatching them at b<512 hides
// that latency under the 11264 streaming cvt blocks.
//   [0,512):             WqT/WkT fp32 -> fp16 TRANSPOSED [e][k].
//   [512,512+8192):      X fp32 -> fp16.
//   [8704,8704+3072):    Wq,Wk,Wv fp32 -> fp16 (k-major, as input).
// ---------------------------------------------------------------------------
__global__ __launch_bounds__(256) void cvt_all(
    const float* __restrict__ X,
    const float* __restrict__ W0, const float* __restrict__ W1,
    const float* __restrict__ W2,
    unsigned short* __restrict__ Xf, unsigned short* __restrict__ Wf,
    unsigned short* __restrict__ WqT, unsigned short* __restrict__ WkT)
{
    __shared__ __attribute__((aligned(16))) unsigned short T[64][72];
    const int b = blockIdx.x;
    const int t = threadIdx.x;
    if (b >= 512) {
        const int cb = b - 512;
        const float* src;
        unsigned short* dst;
        int i;
        if (cb < 8192) {
            src = X; dst = Xf;
            i = cb * 256 + t;
        } else {
            const int wb = cb - 8192;
            const int z = wb >> 10;
            src = (z == 0) ? W0 : (z == 1) ? W1 : W2;
            dst = Wf + (size_t)z * DIM * DIM;
            i = (wb & 1023) * 256 + t;
        }
        float4 f = ((const float4*)src)[i];
        u16x4v h;
        h.x = f2h(f.x); h.y = f2h(f.y); h.z = f2h(f.z); h.w = f2h(f.w);
        ((u16x4v*)dst)[i] = h;
        return;
    }
    const int tb = b;                            // 0..511
    const float* src = (tb < 256) ? W0 : W1;     // Wq then Wk
    unsigned short* dst = (tb < 256) ? WqT : WkT;
    const int tile = tb & 255;
    const int tk = (tile >> 4) * 64;
    const int te = (tile & 15) * 64;
    const int cu = t & 15, kr4 = t >> 4;
#pragma unroll
    for (int p = 0; p < 4; ++p) {
        const int k = p * 16 + kr4;
        float4 v = *(const float4*)(src + (size_t)(tk + k) * DIM + te + cu * 4);
        T[cu * 4 + 0][k] = f2h(v.x);
        T[cu * 4 + 1][k] = f2h(v.y);
        T[cu * 4 + 2][k] = f2h(v.z);
        T[cu * 4 + 3][k] = f2h(v.w);
    }
    __syncthreads();
    const int un = t & 7, er = t >> 3;
#pragma unroll
    for (int p = 0; p < 2; ++p) {
        const int e = p * 32 + er;
        *(u16x8v*)(dst + (size_t)(te + e) * DIM + tk + un * 8) =
            *(const u16x8v*)&T[e][un * 8];
    }
}

// ---------------------------------------------------------------------------
// Mt[e'][e] = sum_k Wk[k][e'] Wq[k][e], NT GEMM on transposed copies.
// ---------------------------------------------------------------------------
__global__ __launch_bounds__(256) void mt_gemm(
    const unsigned short* __restrict__ WkTp, const unsigned short* __restrict__ WqTp,
    unsigned short* __restrict__ Mt)
{
    __shared__ __attribute__((aligned(16))) unsigned short Ah[128 * 64];
    __shared__ __attribute__((aligned(16))) unsigned short Bh[128 * 64];
    const int m0 = blockIdx.x * 128, n0 = blockIdx.y * 128;
    const int tid = threadIdx.x;
    const int w = tid >> 6, lane = tid & 63, q = lane >> 4, c = lane & 15;
    const int wrow = (w >> 1) * 64, wcol = (w & 1) * 64;
    const int g8 = lane >> 3;
    const int cu = (lane & 7) ^ g8;
    const int srow = w * 8 + g8;
    const int scol = cu * 8;
    unsigned short* lA = Ah + w * 512;
    unsigned short* lB = Bh + w * 512;
    const int c7 = c & 7;

    f32x4 acc[4][4];
#pragma unroll
    for (int a = 0; a < 4; ++a)
#pragma unroll
        for (int bq = 0; bq < 4; ++bq) acc[a][bq] = (f32x4){0.f, 0.f, 0.f, 0.f};

    for (int k0 = 0; k0 < DIM; k0 += 64) {
        __syncthreads();
        {
            const size_t ga = (size_t)(m0 + srow) * DIM + k0 + scol;
            const size_t gb = (size_t)(n0 + srow) * DIM + k0 + scol;
#pragma unroll
            for (int j = 0; j < 4; ++j) {
                gld_lds16(WkTp + ga + (size_t)(j * 32) * DIM, lA + j * 2048);
                gld_lds16(WqTp + gb + (size_t)(j * 32) * DIM, lB + j * 2048);
            }
        }
        __syncthreads();
#pragma unroll
        for (int kk = 0; kk < 2; ++kk) {
            f16x8 af[4], bf[4];
#pragma unroll
            for (int mi = 0; mi < 4; ++mi)
                af[mi] = ldsld(Ah + (wrow + mi * 16 + c) * 64 + (((kk << 2) + q) ^ c7) * 8);
#pragma unroll
            for (int ni = 0; ni < 4; ++ni)
                bf[ni] = ldsld(Bh + (wcol + ni * 16 + c) * 64 + (((kk << 2) + q) ^ c7) * 8);
#pragma unroll
            for (int mi = 0; mi < 4; ++mi)
#pragma unroll
                for (int ni = 0; ni < 4; ++ni)
                    acc[mi][ni] = __builtin_amdgcn_mfma_f32_16x16x32_f16(af[mi], bf[ni], acc[mi][ni], 0, 0, 0);
        }
    }
#pragma unroll
    for (int mi = 0; mi < 4; ++mi)
#pragma unroll
        for (int ni = 0; ni < 4; ++ni) {
            const int col = n0 + wcol + ni * 16 + c;
#pragma unroll
            for (int r = 0; r < 4; ++r) {
                const int row = m0 + wrow + mi * 16 + q * 4 + r;
                Mt[(size_t)row * DIM + col] = f2h(acc[mi][ni][r]);
            }
        }
}

// ---------------------------------------------------------------------------
// Y/V projection, 256x256 tile, 8-phase counted-vmcnt schedule (r11,
// refcheck'd). z=0: Y = NT(Xf, Mt); z=1: V = NT(Xf, Wvf) -> Vt[b][d][s].
// ---------------------------------------------------------------------------
__global__ __launch_bounds__(512) void yv8_gemm(
    const unsigned short* __restrict__ Xf, const unsigned short* __restrict__ Mt,
    const unsigned short* __restrict__ Wvf,
    unsigned short* __restrict__ Yf, unsigned short* __restrict__ Vt)
{
    __shared__ __attribute__((aligned(16))) unsigned short L[65536];  // 128 KB
    unsigned short* A0 = L;
    unsigned short* B0 = L + 16384;
    unsigned short* A1 = L + 32768;
    unsigned short* B1 = L + 49152;

    const int m0 = blockIdx.x * 256, n0 = blockIdx.y * 256, z = blockIdx.z;
    const unsigned short* Bg = z ? Wvf : Mt;
    const int tid = threadIdx.x;
    const int w = tid >> 6, lane = tid & 63;
    const int wm = w >> 2, wn = w & 3;          // 2M x 4N waves
    const int c = lane & 15, q = lane >> 4, c7 = c & 7;
    const int sl8 = lane >> 3;                  // staging row-in-8
    const int gu = ((lane & 7) ^ sl8) * 8;      // inverse-swizzled col (shorts)

    auto stage = [&](const unsigned short* G, int roff, int T, unsigned short* Lb, int h) {
        const int rb0 = h * 128 + w * 16;
        const int kb = T * 64 + gu;
        gld_lds16(G + (size_t)(roff + rb0 + sl8) * DIM + kb, Lb + rb0 * 64 + lane * 8);
        gld_lds16(G + (size_t)(roff + rb0 + 8 + sl8) * DIM + kb, Lb + (rb0 + 8) * 64 + lane * 8);
    };
    auto rdA = [&](const unsigned short* LA, int fr, int kk) {
        const int row = wm * 128 + fr * 16 + c;
        return ldsld(LA + row * 64 + (((kk << 2) + q) ^ c7) * 8);
    };
    auto rdB = [&](const unsigned short* LB, int fb, int kk) {
        const int row = wn * 64 + fb * 16 + c;
        return ldsld(LB + row * 64 + (((kk << 2) + q) ^ c7) * 8);
    };

    f32x4 acc[8][4];
#pragma unroll
    for (int a = 0; a < 8; ++a)
#pragma unroll
        for (int bq = 0; bq < 4; ++bq) acc[a][bq] = (f32x4){0.f, 0.f, 0.f, 0.f};
    f16x8 bfr[4][2];

#define PH(LAp, LBp, p, STAGES, LOADB)                                          \
    {                                                                           \
        if (LOADB) {                                                            \
            _Pragma("unroll") for (int fb = 0; fb < 4; ++fb) {                  \
                bfr[fb][0] = rdB(LBp, fb, 0);                                   \
                bfr[fb][1] = rdB(LBp, fb, 1);                                   \
            }                                                                   \
        }                                                                       \
        f16x8 a00 = rdA(LAp, 2 * (p), 0),     a01 = rdA(LAp, 2 * (p), 1);       \
        f16x8 a10 = rdA(LAp, 2 * (p) + 1, 0), a11 = rdA(LAp, 2 * (p) + 1, 1);   \
        STAGES;                                                                 \
        barrier_mf();                                                           \
        __builtin_amdgcn_s_setprio(1);                                          \
        _Pragma("unroll") for (int fb = 0; fb < 4; ++fb) {                      \
            acc[2*(p)][fb]   = __builtin_amdgcn_mfma_f32_16x16x32_f16(a00, bfr[fb][0], acc[2*(p)][fb],   0, 0, 0); \
            acc[2*(p)][fb]   = __builtin_amdgcn_mfma_f32_16x16x32_f16(a01, bfr[fb][1], acc[2*(p)][fb],   0, 0, 0); \
            acc[2*(p)+1][fb] = __builtin_amdgcn_mfma_f32_16x16x32_f16(a10, bfr[fb][0], acc[2*(p)+1][fb], 0, 0, 0); \
            acc[2*(p)+1][fb] = __builtin_amdgcn_mfma_f32_16x16x32_f16(a11, bfr[fb][1], acc[2*(p)+1][fb], 0, 0, 0); \
        }                                                                       \
        __builtin_amdgcn_s_setprio(0);                                          \
        barrier_mf();                                                           \
    }

    stage(Xf, m0, 0, A0, 0); stage(Xf, m0, 0, A0, 1);
    stage(Bg, n0, 0, B0, 0); stage(Bg, n0, 0, B0, 1);
    stage(Bg, n0, 1, B1, 0); stage(Bg, n0, 1, B1, 1);

    for (int it = 0; it < 8; ++it) {
        const int u = 2 * it;
        const bool nt = it < 7;
        asm volatile("s_waitcnt vmcnt(4)" ::: "memory");
        barrier_mf();
        PH(A0, B0, 0, { stage(Xf, m0, u + 1, A1, 0); }, true);
        PH(A0, B0, 1, { stage(Xf, m0, u + 1, A1, 1); }, false);
        PH(A0, B0, 2, { if (nt) stage(Bg, n0, u + 2, B0, 0); }, false);
        PH(A0, B0, 3, { if (nt) stage(Bg, n0, u + 2, B0, 1); }, false);
        if (nt) asm volatile("s_waitcnt vmcnt(4)" ::: "memory");
        else    asm volatile("s_waitcnt vmcnt(0)" ::: "memory");
        barrier_mf();
        PH(A1, B1, 0, { if (nt) stage(Xf, m0, u + 2, A0, 0); }, true);
        PH(A1, B1, 1, { if (nt) stage(Xf, m0, u + 2, A0, 1); }, false);
        PH(A1, B1, 2, { if (nt) stage(Bg, n0, u + 3, B1, 0); }, false);
        PH(A1, B1, 3, { if (nt) stage(Bg, n0, u + 3, B1, 1); }, false);
    }
#undef PH

    if (z == 1) {
#pragma unroll
        for (int fr = 0; fr < 8; ++fr) {
            const int mg = m0 + wm * 128 + fr * 16 + q * 4;
            const int bb = mg >> 11, ss = mg & (SEQ - 1);
#pragma unroll
            for (int fb = 0; fb < 4; ++fb) {
                const int col = n0 + wn * 64 + fb * 16 + c;
                u16x4v v;
                v.x = f2h(acc[fr][fb][0]);
                v.y = f2h(acc[fr][fb][1]);
                v.z = f2h(acc[fr][fb][2]);
                v.w = f2h(acc[fr][fb][3]);
                *(u16x4v*)(Vt + ((size_t)bb * DIM + col) * SEQ + ss) = v;
            }
        }
    } else {
#pragma unroll
        for (int fr = 0; fr < 8; ++fr)
#pragma unroll
            for (int fb = 0; fb < 4; ++fb) {
                const int col = n0 + wn * 64 + fb * 16 + c;
#pragma unroll
                for (int r = 0; r < 4; ++r) {
                    const int row = m0 + wm * 128 + fr * 16 + q * 4 + r;
                    Yf[(size_t)row * DIM + col] = f2h(acc[fr][fb][r]);
                }
            }
    }
}

// ---------------------------------------------------------------------------
// Scores GEMM: S = Yf Xf^T * SCALE, fp16 out, scores==0 masked to 0xFC00 on
// the f32 accumulator. 1-D grid 544 = 8 XCD chunks x 68 consecutive
// triangular-t blocks (bijective): panel reuse stays within one L2.
// ---------------------------------------------------------------------------
__global__ __launch_bounds__(256) void scores_gemm1b(
    const unsigned short* __restrict__ Q, const unsigned short* __restrict__ K,
    unsigned short* __restrict__ S)
{
    __shared__ __attribute__((aligned(16))) unsigned short Ah[128 * 64];
    __shared__ __attribute__((aligned(16))) unsigned short Bh[128 * 64];
    const int flat = blockIdx.x;               // 0..543
    const int wg = (flat & 7) * 68 + (flat >> 3);  // XCD-chunked, bijective
    const int b = wg / 136;
    const int t = wg - b * 136;                // 0..135 triangular index
    int ti = (int)((__builtin_sqrtf(8.f * t + 1.f) - 1.f) * 0.5f);
    while ((ti + 1) * (ti + 2) / 2 <= t) ++ti;
    while (ti * (ti + 1) / 2 > t) --ti;
    const int tj = t - ti * (ti + 1) / 2;
    const int i0 = ti * 128, j0 = tj * 128;
    const unsigned short* Qb = Q + (size_t)b * SEQ * DIM;
    const unsigned short* Kb = K + (size_t)b * SEQ * DIM;
    unsigned short* Sb = S + (size_t)b * SEQ * SEQ;
    const int tid = threadIdx.x;
    const int w = tid >> 6, lane = tid & 63, q = lane >> 4, c = lane & 15;
    const int wrow = (w >> 1) * 64, wcol = (w & 1) * 64;
    const int g8 = lane >> 3;
    const int cu = (lane & 7) ^ g8;
    const int srow = w * 8 + g8;
    const int scol = cu * 8;
    unsigned short* lA = Ah + w * 512;
    unsigned short* lB = Bh + w * 512;
    const int c7 = c & 7;

    f32x4 acc[4][4];
#pragma unroll
    for (int a = 0; a < 4; ++a)
#pragma unroll
        for (int bq = 0; bq < 4; ++bq) acc[a][bq] = (f32x4){0.f, 0.f, 0.f, 0.f};

    for (int k0 = 0; k0 < DIM; k0 += 64) {
        __syncthreads();
        {
            const size_t ga = (size_t)(i0 + srow) * DIM + k0 + scol;
            const size_t gb = (size_t)(j0 + srow) * DIM + k0 + scol;
#pragma unroll
            for (int j = 0; j < 4; ++j) {
                gld_lds16(Qb + ga + (size_t)(j * 32) * DIM, lA + j * 2048);
                gld_lds16(Kb + gb + (size_t)(j * 32) * DIM, lB + j * 2048);
            }
        }
        __syncthreads();
#pragma unroll
        for (int kk = 0; kk < 2; ++kk) {
            f16x8 ah[4], bh[4];
#pragma unroll
            for (int mi = 0; mi < 4; ++mi)
                ah[mi] = ldsld(Ah + (wrow + mi * 16 + c) * 64 + (((kk << 2) + q) ^ c7) * 8);
#pragma unroll
            for (int ni = 0; ni < 4; ++ni)
                bh[ni] = ldsld(Bh + (wcol + ni * 16 + c) * 64 + (((kk << 2) + q) ^ c7) * 8);
#pragma unroll
            for (int mi = 0; mi < 4; ++mi)
#pragma unroll
                for (int ni = 0; ni < 4; ++ni)
                    acc[mi][ni] = __builtin_amdgcn_mfma_f32_16x16x32_f16(ah[mi], bh[ni], acc[mi][ni], 0, 0, 0);
        }
    }
#pragma unroll
    for (int mi = 0; mi < 4; ++mi)
#pragma unroll
        for (int ni = 0; ni < 4; ++ni) {
            const int col = j0 + wcol + ni * 16 + c;
#pragma unroll
            for (int r = 0; r < 4; ++r) {
                const int row = i0 + wrow + mi * 16 + q * 4 + r;
                const float sc = acc[mi][ni][r] * 0.03125f;
                Sb[(size_t)row * SEQ + col] =
                    (sc == 0.f) ? (unsigned short)0xFC00u : f2h(sc);
            }
        }
}

// ---------------------------------------------------------------------------
// Row-wise masked softmax: fp16 S -> fp16 P. j > i masked; scores==0 already
// -inf. Skip loads beyond i, skip writes beyond rowtile end. Grid (SEQ, BATCH).
// ---------------------------------------------------------------------------
__global__ __launch_bounds__(256) void softmax_row_b(
    const unsigned short* __restrict__ S, unsigned short* __restrict__ P)
{
    const int i = blockIdx.x, t = threadIdx.x;
    const size_t ro = ((size_t)blockIdx.y * SEQ + i) * SEQ;
    const int wid = t >> 6, lane = t & 63;
    __shared__ float redm[4], reds[4];
    const int j0 = t * 8;
    const int rti = (i & ~127) + 128;        // pv reads cols < rti only
    float sv[8];
    float mx = -__builtin_inff();
    if (j0 <= i) {
        u16x8v raw = *(const u16x8v*)(S + ro + j0);
#pragma unroll
        for (int u = 0; u < 8; ++u) {
            float s = (j0 + u <= i) ? h2f(raw[u]) : -__builtin_inff();
            sv[u] = s;
            mx = fmaxf(mx, s);
        }
    } else {
#pragma unroll
        for (int u = 0; u < 8; ++u) sv[u] = -__builtin_inff();
    }
#pragma unroll
    for (int off = 1; off < 64; off <<= 1) mx = fmaxf(mx, __shfl_xor(mx, off));
    if (lane == 0) redm[wid] = mx;
    __syncthreads();
    const float M = fmaxf(fmaxf(redm[0], redm[1]), fmaxf(redm[2], redm[3]));
    float sum = 0.f;
#pragma unroll
    for (int u = 0; u < 8; ++u) {
        float e = __expf(sv[u] - M);
        sv[u] = e;
        sum += e;
    }
#pragma unroll
    for (int off = 1; off < 64; off <<= 1) sum += __shfl_xor(sum, off);
    if (lane == 0) reds[wid] = sum;
    __syncthreads();
    const float rinv = 1.f / (reds[0] + reds[1] + reds[2] + reds[3]);
    if (j0 < rti) {
        u16x8v o;
#pragma unroll
        for (int u = 0; u < 8; ++u) o[u] = f2h(sv[u] * rinv);
        *(u16x8v*)(P + ro + j0) = o;
    }
}

// ---------------------------------------------------------------------------
// out = P @ V via Vt (NT MFMA, fp16), fp32 store. 128x128 tile, BK=64
// swizzled; k-loop truncated at causal bound. 512 blocks (2/CU), XCD-chunked.
// COMPLEMENTARY intra-XCD ordering (r13): within XCD chunk idx in [0,64),
//   idx < 32: i0t = idx&15,       g = idx>>4        (groups 0,1)
//   idx >=32: i0t = 15-(idx&15),  g = 2+((idx&31)>>4) (groups 2,3)
// Under round-robin CU fill (idx%32 = CU slot) each CU gets idx=c and
// idx=c+32 -> i0t and 15-i0t -> constant 34 K-steps/CU. r12's ordering gave
// every CU the SAME i0t twice (4..68 steps/CU skew: pv 45us at 14.7% MfmaUtil).
// Group ownership per XCD unchanged (L2 locality preserved).
// ---------------------------------------------------------------------------
__global__ __launch_bounds__(256) void pv_gemm(
    const unsigned short* __restrict__ Pm, const unsigned short* __restrict__ Vt,
    float* __restrict__ Out)
{
    __shared__ __attribute__((aligned(16))) unsigned short Ps[128 * 64];
    __shared__ __attribute__((aligned(16))) unsigned short Vs[128 * 64];
    const int flat = blockIdx.x;             // 0..511
    const int x = flat & 7;                  // XCD
    const int idx = flat >> 3;               // 0..63 within XCD
    const int half = idx >> 5;
    const int i0t = half ? 15 - (idx & 15) : (idx & 15);
    const int g = half ? 2 + ((idx & 31) >> 4) : (idx >> 4);
    const int grp = x * 4 + g;               // 0..31
    const int b = grp >> 3;
    const int d0 = (grp & 7) * 128;
    const int i0 = i0t * 128;
    const int tid = threadIdx.x;
    const int w = tid >> 6, lane = tid & 63, q = lane >> 4, c = lane & 15;
    const int wrow = (w >> 1) * 64, wcol = (w & 1) * 64;
    const int g8 = lane >> 3;
    const int cu = (lane & 7) ^ g8;
    const int srow = w * 8 + g8;
    const int scol = cu * 8;
    unsigned short* lA = Ps + w * 512;
    unsigned short* lB = Vs + w * 512;
    const int c7 = c & 7;

    f32x4 acc[4][4];
#pragma unroll
    for (int a = 0; a < 4; ++a)
#pragma unroll
        for (int bq = 0; bq < 4; ++bq) acc[a][bq] = (f32x4){0.f, 0.f, 0.f, 0.f};

    const int njs = 2 * i0t + 2;  // covers cols < i0+128

    for (int ks = 0; ks < njs; ++ks) {
        const int j0 = ks * 64;
        __syncthreads();
        {
            const size_t gpa = ((size_t)b * SEQ + i0 + srow) * SEQ + j0 + scol;
            const size_t gva = ((size_t)b * DIM + d0 + srow) * SEQ + j0 + scol;
#pragma unroll
            for (int j = 0; j < 4; ++j) {
                gld_lds16(Pm + gpa + (size_t)(j * 32) * SEQ, lA + j * 2048);
                gld_lds16(Vt + gva + (size_t)(j * 32) * SEQ, lB + j * 2048);
            }
        }
        __syncthreads();
#pragma unroll
        for (int kk = 0; kk < 2; ++kk) {
            f16x8 ah[4], bh[4];
#pragma unroll
            for (int mi = 0; mi < 4; ++mi)
                ah[mi] = ldsld(Ps + (wrow + mi * 16 + c) * 64 + (((kk << 2) + q) ^ c7) * 8);
#pragma unroll
            for (int ni = 0; ni < 4; ++ni)
                bh[ni] = ldsld(Vs + (wcol + ni * 16 + c) * 64 + (((kk << 2) + q) ^ c7) * 8);
#pragma unroll
            for (int mi = 0; mi < 4; ++mi)
#pragma unroll
                for (int ni = 0; ni < 4; ++ni)
                    acc[mi][ni] = __builtin_amdgcn_mfma_f32_16x16x32_f16(ah[mi], bh[ni], acc[mi][ni], 0, 0, 0);
        }
    }
#pragma unroll
    for (int mi = 0; mi < 4; ++mi)
#pragma unroll
        for (int ni = 0; ni < 4; ++ni) {
            const int dcol = d0 + wcol + ni * 16 + c;
#pragma unroll
            for (int r = 0; r < 4; ++r) {
                const int i = i0 + wrow + mi * 16 + q * 4 + r;
                Out[((size_t)b * SEQ + i) * DIM + dcol] = acc[mi][ni][r];
            }
        }
}

extern "C" void kernel_launch(void* const* d_in, const int* in_sizes, int n_in,
                              void* d_out, int out_size, void* d_ws, size_t ws_size,
                              hipStream_t stream)
{
    (void)out_size; (void)ws_size;
    const float* X = nullptr;
    const float* Wv[3] = {nullptr, nullptr, nullptr};
    int nw = 0;
    for (int i = 0; i < n_in; ++i) {
        if (in_sizes[i] == (int)NBS)
            X = (const float*)d_in[i];
        else if (nw < 3)
            Wv[nw++] = (const float*)d_in[i];
    }

    unsigned short* ws = (unsigned short*)d_ws;
    unsigned short* Yf = ws;                 // 16 MB
    unsigned short* Vt = ws + 2 * NBS;       // 16 MB
    unsigned short* Xf = ws + 3 * NBS;       // consumed by yv + scores
    unsigned short* Pp = ws + 3 * NBS;       // P aliases Xf after scores (32 MB)
    unsigned short* Sb = ws + 5 * NBS;       // fp16 S, all batches (32 MB)
    unsigned short* Wf = ws + 7 * NBS;       // 6 MB (Wq,Wk,Wv fp16)
    unsigned short* Mtb = Wf + (size_t)3 * DIM * DIM;   // 2 MB
    unsigned short* WqT = Mtb + (size_t)DIM * DIM;      // 2 MB
    unsigned short* WkT = WqT + (size_t)DIM * DIM;      // 2 MB
    float* Out = (float*)d_out;

    // Wv[0]=WQ, Wv[1]=WK, Wv[2]=WV (input order).
    cvt_all<<<dim3(512 + 8192 + 3072), 256, 0, stream>>>(
        X, Wv[0], Wv[1], Wv[2], Xf, Wf, WqT, WkT);

    mt_gemm<<<dim3(8, 8), 256, 0, stream>>>(WkT, WqT, Mtb);

    yv8_gemm<<<dim3(32, 4, 2), 512, 0, stream>>>(
        Xf, Mtb, Wf + (size_t)2 * DIM * DIM, Yf, Vt);

    scores_gemm1b<<<dim3(544), 256, 0, stream>>>(Yf, Xf, Sb);
    softmax_row_b<<<dim3(SEQ, BATCH), 256, 0, stream>>>(Sb, Pp);

    pv_gemm<<<dim3(512), 256, 0, stream>>>(Pp, Vt, Out);
}